// Round 5
// baseline (1319.310 us; speedup 1.0000x reference)
//
#include <hip/hip_runtime.h>
#include <math.h>

#define TT 512
#define BB 128
#define OBSD 512
#define HD 256
#define PD 128
#define LD 4
#define NTB (TT*BB)   // 65536

typedef __bf16 bf16x8 __attribute__((ext_vector_type(8)));
typedef float  f32x4  __attribute__((ext_vector_type(4)));

__device__ __forceinline__ float bf2f(unsigned short u) {
    return __uint_as_float(((unsigned)u) << 16);
}
__device__ __forceinline__ unsigned short f2bf(float f) {
    unsigned u = __float_as_uint(f);
    unsigned r = (u + 0x7FFFu + ((u >> 16) & 1u)) >> 16;
    return (unsigned short)r;
}
__device__ __forceinline__ float gelu_f(float x) {
    float x3 = x * x * x;
    return 0.5f * x * (1.f + tanhf(0.7978845608028654f * (x + 0.044715f * x3)));
}

// ======== Fused GEMM, tile 64 x (NJ*64), 512 threads, NO LDS staging ========
// Register-fragment loads straight from global:
//  - A rows are shared by all 8 waves of the block -> L1-served (4KB/K-step),
//    HBM traffic unchanged vs LDS staging.
//  - B^T (weights, <=128KB) is L2-hot across all 1024 blocks.
//  - Per-fragment base pointer + compile-time offset immediates (kt*64B).
//  - ZERO barriers in the K-loop: waves fully independent (R1/R4 showed
//    barrier-coupled staging is the bottleneck; depth tuning moved <1%).
// acc[mi][nj][r] = C[row = mi*16+(lane&15)][col = w*NJW*16 + nj*16 + quad*4 + r]
// MODE 0 (enc1): x = leaky(acc+bias);  write X; u = LN(x)           -> U
// MODE 1 (Bu):   write bf(acc)                                      -> U
// MODE 2 (ys):   v = acc + bias[c]*aux1; z = gelu(LN(v))            -> U
// MODE 3 (GLU):  x = Xold + aux1*sigmoid(acc+bias); write X; LN->U if wU
// MODE 4 (head): leaky(acc+bias)                                    -> U
template<int MODE, int NJ, int NK>
__global__ __launch_bounds__(512) void mgemm2(
    const unsigned short* __restrict__ A, const unsigned short* __restrict__ BT,
    int LDA, const float* __restrict__ bias,
    const float* __restrict__ lnsc, const float* __restrict__ lnbi,
    const unsigned short* __restrict__ aux1, unsigned short* Xio,
    unsigned short* __restrict__ U, int wU)
{
    constexpr int NJW = NJ / 2;          // 16-col tiles per wave
    constexpr int K = NK * 32;           // B^T leading dim (compile-time)
    const int N = NJ * 64;
    __shared__ float2 red[64][8];
    int tid = threadIdx.x;
    int lane = tid & 63, w = tid >> 6;   // w in [0,8)
    int m16 = lane & 15, quad = lane >> 4;
    int m0 = blockIdx.x * 64;

    f32x4 acc[4][NJW] = {};

    // per-fragment base pointers (lane-dependent); loads use kt*64B immediates
    const unsigned short* ap[4];
#pragma unroll
    for (int mi = 0; mi < 4; ++mi)
        ap[mi] = A + (size_t)(m0 + mi * 16 + m16) * LDA + quad * 8;
    const unsigned short* bp[NJW];
#pragma unroll
    for (int nj = 0; nj < NJW; ++nj)
        bp[nj] = BT + (size_t)(w * (NJW * 16) + nj * 16 + m16) * K + quad * 8;

#pragma unroll
    for (int kt = 0; kt < NK; ++kt) {
        bf16x8 af[4], bfr[NJW];
#pragma unroll
        for (int mi = 0; mi < 4; ++mi)
            af[mi] = *(const bf16x8*)(ap[mi] + kt * 32);
#pragma unroll
        for (int nj = 0; nj < NJW; ++nj)
            bfr[nj] = *(const bf16x8*)(bp[nj] + kt * 32);
#pragma unroll
        for (int mi = 0; mi < 4; ++mi)
#pragma unroll
            for (int nj = 0; nj < NJW; ++nj)
                acc[mi][nj] = __builtin_amdgcn_mfma_f32_16x16x32_bf16(
                    bfr[nj], af[mi], acc[mi][nj], 0, 0, 0);   // transposed: C^T
    }

    int colb = w * (NJW * 16) + quad * 4;    // + nj*16

    if (MODE == 1) {
#pragma unroll
        for (int mi = 0; mi < 4; ++mi) {
            size_t rowb = (size_t)(m0 + mi * 16 + m16) * N;
#pragma unroll
            for (int nj = 0; nj < NJW; ++nj) {
                ushort4 o = { f2bf(acc[mi][nj][0]), f2bf(acc[mi][nj][1]),
                              f2bf(acc[mi][nj][2]), f2bf(acc[mi][nj][3]) };
                *(ushort4*)(U + rowb + colb + nj * 16) = o;
            }
        }
        return;
    }

    // ---- phase 1: transform acc -> v, write X/U, accumulate row stats ----
#pragma unroll
    for (int mi = 0; mi < 4; ++mi) {
        size_t rowb = (size_t)(m0 + mi * 16 + m16) * N;
        float s = 0.f, q = 0.f;
#pragma unroll
        for (int nj = 0; nj < NJW; ++nj) {
            float4 bn = *(const float4*)(bias + colb + nj * 16);
            ushort4 a1, xo;
            if (MODE == 2 || MODE == 3) a1 = *(const ushort4*)(aux1 + rowb + colb + nj * 16);
            if (MODE == 3)              xo = *(const ushort4*)(Xio + rowb + colb + nj * 16);
            float vv[4];
#pragma unroll
            for (int r = 0; r < 4; ++r) {
                float v = acc[mi][nj][r];
                float bv = (r == 0) ? bn.x : (r == 1) ? bn.y : (r == 2) ? bn.z : bn.w;
                if (MODE == 0 || MODE == 4) {
                    v += bv; v = v > 0.f ? v : 0.01f * v;
                } else if (MODE == 2) {
                    float u = bf2f(r == 0 ? a1.x : r == 1 ? a1.y : r == 2 ? a1.z : a1.w);
                    v += bv * u;
                } else if (MODE == 3) {
                    float zz = bf2f(r == 0 ? a1.x : r == 1 ? a1.y : r == 2 ? a1.z : a1.w);
                    float xx = bf2f(r == 0 ? xo.x : r == 1 ? xo.y : r == 2 ? xo.z : xo.w);
                    float sg = 1.f / (1.f + expf(-(v + bv)));
                    v = xx + zz * sg;
                }
                vv[r] = v;
                acc[mi][nj][r] = v;
                s += v; q += v * v;
            }
            if (MODE == 0 || MODE == 3) {
                ushort4 o = { f2bf(vv[0]), f2bf(vv[1]), f2bf(vv[2]), f2bf(vv[3]) };
                *(ushort4*)(Xio + rowb + colb + nj * 16) = o;
            } else if (MODE == 4) {
                ushort4 o = { f2bf(vv[0]), f2bf(vv[1]), f2bf(vv[2]), f2bf(vv[3]) };
                *(ushort4*)(U + rowb + colb + nj * 16) = o;
            }
        }
        if (MODE != 4 && (MODE != 3 || wU)) {
            s += __shfl_xor(s, 16); q += __shfl_xor(q, 16);
            s += __shfl_xor(s, 32); q += __shfl_xor(q, 32);
            if (quad == 0) red[mi * 16 + m16][w] = float2{s, q};
        }
    }
    if (MODE == 4 || (MODE == 3 && !wU)) return;
    __syncthreads();

    // ---- phase 2: finalize LN, write U ----
#pragma unroll
    for (int mi = 0; mi < 4; ++mi) {
        int row_l = mi * 16 + m16;
        float S = 0.f, Q = 0.f;
#pragma unroll
        for (int ww = 0; ww < 8; ++ww) {
            float2 tv = red[row_l][ww];
            S += tv.x; Q += tv.y;
        }
        float mu = S * (1.f / 256.f);
        float var = Q * (1.f / 256.f) - mu * mu;
        float rstd = rsqrtf(var + 1e-6f);
        size_t rowb = (size_t)(m0 + row_l) * N;
#pragma unroll
        for (int nj = 0; nj < NJW; ++nj) {
            float4 ls = *(const float4*)(lnsc + colb + nj * 16);
            float4 lb = *(const float4*)(lnbi + colb + nj * 16);
            float o[4];
#pragma unroll
            for (int r = 0; r < 4; ++r) {
                float sc = (r == 0) ? ls.x : (r == 1) ? ls.y : (r == 2) ? ls.z : ls.w;
                float bi = (r == 0) ? lb.x : (r == 1) ? lb.y : (r == 2) ? lb.z : lb.w;
                float v = (acc[mi][nj][r] - mu) * rstd * sc + bi;
                if (MODE == 2) v = gelu_f(v);
                o[r] = v;
            }
            ushort4 ov = { f2bf(o[0]), f2bf(o[1]), f2bf(o[2]), f2bf(o[3]) };
            *(ushort4*)(U + rowb + colb + nj * 16) = ov;
        }
    }
}

// ======= enc0: A f32 (obs), staged to bf16 LDS in VGPRs; tile 64x128 ========
__global__ __launch_bounds__(256) void mgemm_obs(
    const float* __restrict__ A, const unsigned short* __restrict__ BT,
    unsigned short* __restrict__ U, const float* __restrict__ bias)
{
    const int K = 512, NJ = 2, N = 128;
    __shared__ unsigned short smA[64 * 32];
    __shared__ unsigned short smB[NJ * 64 * 32];
    int tid = threadIdx.x;
    int lane = tid & 63, w = tid >> 6;
    int m16 = lane & 15, quad = lane >> 4;
    int m0 = blockIdx.x * 64;

    f32x4 acc[4][NJ] = {};
    for (int k0 = 0; k0 < K; k0 += 32) {
#pragma unroll
        for (int p = 0; p < 2; ++p) {
            int idx = p * 256 + tid;
            int r = idx >> 3, kq = (idx & 7) * 4;
            float4 v = *(const float4*)(A + (size_t)(m0 + r) * K + k0 + kq);
            ushort4 o = { f2bf(v.x), f2bf(v.y), f2bf(v.z), f2bf(v.w) };
            *(ushort4*)(smA + r * 32 + kq) = o;
        }
#pragma unroll
        for (int p = 0; p < NJ; ++p) {
            const unsigned short* g = BT + (size_t)(p * 64 + (tid >> 2)) * K + k0 + (tid & 3) * 8;
            unsigned short* l = smB + p * 2048 + tid * 8;
            __builtin_amdgcn_global_load_lds(
                (const __attribute__((address_space(1))) void*)g,
                (__attribute__((address_space(3))) void*)l, 16, 0, 0);
        }
        __syncthreads();
        bf16x8 af[4], bfr[NJ];
#pragma unroll
        for (int mi = 0; mi < 4; ++mi)
            af[mi] = *(const bf16x8*)(smA + (mi * 16 + m16) * 32 + quad * 8);
#pragma unroll
        for (int nj = 0; nj < NJ; ++nj)
            bfr[nj] = *(const bf16x8*)(smB + (w * NJ * 16 + nj * 16 + m16) * 32 + quad * 8);
#pragma unroll
        for (int mi = 0; mi < 4; ++mi)
#pragma unroll
            for (int nj = 0; nj < NJ; ++nj)
                acc[mi][nj] = __builtin_amdgcn_mfma_f32_16x16x32_bf16(
                    bfr[nj], af[mi], acc[mi][nj], 0, 0, 0);
        __syncthreads();
    }
    int colb = w * NJ * 16 + quad * 4;
#pragma unroll
    for (int mi = 0; mi < 4; ++mi) {
        size_t rowb = (size_t)(m0 + mi * 16 + m16) * N;
#pragma unroll
        for (int nj = 0; nj < NJ; ++nj) {
            float4 bv = *(const float4*)(bias + colb + nj * 16);
            float v0 = acc[mi][nj][0] + bv.x; v0 = v0 > 0.f ? v0 : 0.01f * v0;
            float v1 = acc[mi][nj][1] + bv.y; v1 = v1 > 0.f ? v1 : 0.01f * v1;
            float v2 = acc[mi][nj][2] + bv.z; v2 = v2 > 0.f ? v2 : 0.01f * v2;
            float v3 = acc[mi][nj][3] + bv.w; v3 = v3 > 0.f ? v3 : 0.01f * v3;
            ushort4 o = { f2bf(v0), f2bf(v1), f2bf(v2), f2bf(v3) };
            *(ushort4*)(U + rowb + colb + nj * 16) = o;
        }
    }
}

// ------------- Chunk-parallel scan: 512 blocks (B x 4 p-phases) -------------
// 16 chunks x 32 t-steps (was 8x64): half the serial chain, buf[32] (-32 VGPR),
// 2 blocks/CU -> 2x the resident waves of the 256-block version.
__global__ __launch_bounds__(512) void scan2_k(
    const unsigned short* __restrict__ bu, unsigned short* __restrict__ xs,
    const float* __restrict__ dones,
    const float* __restrict__ h0re, const float* __restrict__ h0im,
    const float* __restrict__ lamre, const float* __restrict__ lamim,
    const float* __restrict__ lstep,
    float* __restrict__ outre, float* __restrict__ outim)
{
    __shared__ float sdone[TT];
    __shared__ float4 ssum[16][32];
    __shared__ float2 shin[16][32];
    int tid = threadIdx.x;
    int b  = blockIdx.x >> 2;
    int ph = blockIdx.x & 3;
    int chunk = tid >> 5, pl = tid & 31;
    int p = ph * 32 + pl;
    sdone[tid] = dones[tid * BB + b];
    float lr = lamre[p], li = lamim[p];
    float st = expf(lstep[p]);
    float er = expf(lr * st);
    float ar = er * cosf(li * st);
    float ai = er * sinf(li * st);
    __syncthreads();

    int t0 = chunk * 32;
    unsigned buf[32];
    float Ar = 1.f, Ai = 0.f, br = 0.f, bi = 0.f;
#pragma unroll
    for (int j = 0; j < 32; ++j) {
        size_t off = ((size_t)(t0 + j) * BB + b) * 256 + 2 * p;
        unsigned v = *(const unsigned*)(bu + off);
        buf[j] = v;
        float bur = bf2f((unsigned short)(v & 0xFFFFu));
        float bui = bf2f((unsigned short)(v >> 16));
        if (sdone[t0 + j] != 0.f) {
            Ar = 0.f; Ai = 0.f; br = bur; bi = bui;
        } else {
            float nAr = ar * Ar - ai * Ai;
            float nAi = ar * Ai + ai * Ar;
            float nbr = fmaf(ar, br, fmaf(-ai, bi, bur));
            float nbi = fmaf(ar, bi, fmaf(ai, br, bui));
            Ar = nAr; Ai = nAi; br = nbr; bi = nbi;
        }
    }
    ssum[chunk][pl] = float4{Ar, Ai, br, bi};
    __syncthreads();
    if (tid < 32) {
        int gid = b * 128 + ph * 32 + tid;
        float hr = h0re[gid], hi = h0im[gid];
#pragma unroll
        for (int c = 0; c < 16; ++c) {
            shin[c][tid] = float2{hr, hi};
            float4 s = ssum[c][tid];
            float nhr = fmaf(s.x, hr, fmaf(-s.y, hi, s.z));
            float nhi = fmaf(s.x, hi, fmaf(s.y, hr, s.w));
            hr = nhr; hi = nhi;
        }
        outre[gid] = hr; outim[gid] = hi;
    }
    __syncthreads();
    float hr = shin[chunk][pl].x, hi = shin[chunk][pl].y;
#pragma unroll
    for (int j = 0; j < 32; ++j) {
        unsigned v = buf[j];
        float bur = bf2f((unsigned short)(v & 0xFFFFu));
        float bui = bf2f((unsigned short)(v >> 16));
        float nr, ni;
        if (sdone[t0 + j] != 0.f) { nr = bur; ni = bui; }
        else {
            nr = fmaf(ar, hr, fmaf(-ai, hi, bur));
            ni = fmaf(ar, hi, fmaf(ai, hr, bui));
        }
        hr = nr; hi = ni;
        size_t off = ((size_t)(t0 + j) * BB + b) * 256 + 2 * p;
        *(unsigned*)(xs + off) = ((unsigned)f2bf(ni) << 16) | f2bf(nr);
    }
}

// -- Precompute B_barT (interleaved n: 2p/2p+1) and CcatT (interleaved k) ----
__global__ __launch_bounds__(256) void prep_k(
    const float* __restrict__ Br, const float* __restrict__ Bi,
    const float* __restrict__ Cr, const float* __restrict__ Ci,
    const float* __restrict__ Lr, const float* __restrict__ Li,
    const float* __restrict__ ls, unsigned short* bbarT, unsigned short* ccatT)
{
    int gid = blockIdx.x * 256 + threadIdx.x;   // L*P*H = 131072
    int l = gid >> 15;
    int rem = gid & 32767;
    int p = rem >> 8;
    int h = rem & 255;
    float lr = Lr[l * PD + p], li = Li[l * PD + p];
    float st = expf(ls[l * PD + p]);
    float er = expf(lr * st);
    float lbr = er * cosf(li * st);
    float lbi = er * sinf(li * st);
    float nr = lbr - 1.f, ni = lbi;
    float den = lr * lr + li * li;
    float fr = (nr * lr + ni * li) / den;
    float fi = (ni * lr - nr * li) / den;
    float bre = Br[(size_t)(l * PD + p) * HD + h];
    float bim = Bi[(size_t)(l * PD + p) * HD + h];
    size_t lb = (size_t)l * 65536;
    bbarT[lb + (size_t)(2 * p) * 256 + h]     = f2bf(fr * bre - fi * bim);
    bbarT[lb + (size_t)(2 * p + 1) * 256 + h] = f2bf(fr * bim + fi * bre);
    float cre = Cr[(size_t)(l * HD + h) * PD + p];
    float cim = Ci[(size_t)(l * HD + h) * PD + p];
    ccatT[lb + (size_t)h * 256 + 2 * p]     = f2bf(2.f * cre);
    ccatT[lb + (size_t)h * 256 + 2 * p + 1] = f2bf(-2.f * cim);
}

// -------- transpose+convert: in f32 [K][N] -> out bf16 [N][K] ---------------
__global__ __launch_bounds__(256) void tcvt_k(const float* __restrict__ in,
    unsigned short* __restrict__ out, int K, int N)
{
    int gid = blockIdx.x * 256 + threadIdx.x;
    if (gid >= K * N) return;
    int k = gid / N, n = gid - k * N;
    out[(size_t)n * K + k] = f2bf(in[gid]);
}

// -------- 4x fused GLU transpose: in f32 [4][256][256] -> bf16 [4][256][256]^T
__global__ __launch_bounds__(256) void tcvt4_k(const float* __restrict__ in,
    unsigned short* __restrict__ out)
{
    int gid = blockIdx.x * 256 + threadIdx.x;   // 4*65536
    int l = gid >> 16;
    int rem = gid & 65535;
    int k = rem >> 8, n = rem & 255;
    out[(size_t)l * 65536 + (size_t)n * 256 + k] = f2bf(in[gid]);
}

// -------- concat two 128-f32 bias vectors into one 256-f32 ------------------
__global__ __launch_bounds__(256) void catb_k(const float* __restrict__ a,
    const float* __restrict__ b, float* __restrict__ out)
{
    int i = threadIdx.x;
    out[i] = (i < 128) ? a[i] : b[i - 128];
}

// ---------------- Final heads: wave per row -> out[row*9 + ...] -------------
__global__ __launch_bounds__(256) void head_k(
    const unsigned short* __restrict__ am2, const unsigned short* __restrict__ v2,
    const float* __restrict__ adW, const float* __restrict__ adb,
    const float* __restrict__ lstd,
    const float* __restrict__ vdW, const float* __restrict__ vdb,
    float* out)
{
    int wid = threadIdx.x >> 6, lane = threadIdx.x & 63;
    size_t row = (size_t)blockIdx.x * 4 + wid;
    float a1 = bf2f(am2[row * 128 + lane]);
    float a2 = bf2f(am2[row * 128 + 64 + lane]);
    float w1 = bf2f(v2[row * 128 + lane]);
    float w2 = bf2f(v2[row * 128 + 64 + lane]);
    float vals[5];
#pragma unroll
    for (int a = 0; a < 4; ++a)
        vals[a] = a1 * adW[lane * 4 + a] + a2 * adW[(lane + 64) * 4 + a];
    vals[4] = w1 * vdW[lane] + w2 * vdW[64 + lane];
#pragma unroll
    for (int off = 32; off; off >>= 1)
#pragma unroll
        for (int k = 0; k < 5; ++k) vals[k] += __shfl_xor(vals[k], off);
    if (lane == 0) {
        size_t o = row * 9;
#pragma unroll
        for (int a = 0; a < 4; ++a) out[o + a] = vals[a] + adb[a];
#pragma unroll
        for (int a = 0; a < 4; ++a) out[o + 4 + a] = expf(lstd[a]);
        out[o + 8] = vals[4] + vdb[0];
    }
}

extern "C" void kernel_launch(void* const* d_in, const int* in_sizes, int n_in,
                              void* d_out, int out_size, void* d_ws, size_t ws_size,
                              hipStream_t stream) {
    (void)in_sizes; (void)n_in; (void)out_size; (void)ws_size;
    const float* obs     = (const float*)d_in[0];
    const float* dones   = (const float*)d_in[1];
    const float* hre     = (const float*)d_in[2];
    const float* him     = (const float*)d_in[3];
    const float* enc0_W  = (const float*)d_in[4];
    const float* enc0_b  = (const float*)d_in[5];
    const float* enc1_W  = (const float*)d_in[6];
    const float* enc1_b  = (const float*)d_in[7];
    const float* nsc     = (const float*)d_in[8];
    const float* nbi     = (const float*)d_in[9];
    const float* Lre     = (const float*)d_in[10];
    const float* Lim     = (const float*)d_in[11];
    const float* B_re    = (const float*)d_in[12];
    const float* B_im    = (const float*)d_in[13];
    const float* C_re    = (const float*)d_in[14];
    const float* C_im    = (const float*)d_in[15];
    const float* Dv      = (const float*)d_in[16];
    const float* lstep   = (const float*)d_in[17];
    const float* glu_W   = (const float*)d_in[18];
    const float* glu_b   = (const float*)d_in[19];
    const float* ab0_W   = (const float*)d_in[20];
    const float* ab0_b   = (const float*)d_in[21];
    const float* ab1_W   = (const float*)d_in[22];
    const float* ab1_b   = (const float*)d_in[23];
    const float* adec_W  = (const float*)d_in[24];
    const float* adec_b  = (const float*)d_in[25];
    const float* log_std = (const float*)d_in[26];
    const float* vb0_W   = (const float*)d_in[27];
    const float* vb0_b   = (const float*)d_in[28];
    const float* vb1_W   = (const float*)d_in[29];
    const float* vb1_b   = (const float*)d_in[30];
    const float* vdec_W  = (const float*)d_in[31];
    const float* vdec_b  = (const float*)d_in[32];

    const size_t MB = (size_t)1 << 20;
    char* wsb = (char*)d_ws;
    unsigned short* XS    = (unsigned short*)(wsb);              // 32MB (per-layer xs)
    unsigned short* AMV1  = (unsigned short*)(wsb);              // 32MB (heads lvl1, after scans)
    unsigned short* AM2   = (unsigned short*)(wsb + 32 * MB);    // 16MB (heads)
    unsigned short* V2    = (unsigned short*)(wsb + 48 * MB);    // 16MB (heads)
    unsigned short* U1    = (unsigned short*)(wsb + 64 * MB);    // 16MB (enc0 out)
    unsigned short* X     = (unsigned short*)(wsb + 96 * MB);    // 32MB residual bf16
    unsigned short* U     = (unsigned short*)(wsb + 128 * MB);   // 32MB (u / z)
    unsigned short* BU    = (unsigned short*)(wsb + 160 * MB);   // 32MB (Bu)
    char* wgt = wsb + 192 * MB;
    unsigned short* BBART = (unsigned short*)(wgt);                  // 512KB
    unsigned short* CCATT = (unsigned short*)(wgt + 512 * 1024);     // 512KB
    unsigned short* GLUT  = (unsigned short*)(wgt + 1024 * 1024);    // 512KB
    unsigned short* E0T   = (unsigned short*)(wgt + 1536 * 1024);    // 128KB
    unsigned short* E1T   = (unsigned short*)(wgt + 1664 * 1024);    // 64KB
    unsigned short* AB0VT = (unsigned short*)(wgt + 1728 * 1024);    // 128KB [AB0T;VB0T]
    unsigned short* AB1T  = (unsigned short*)(wgt + 1856 * 1024);    // 32KB
    unsigned short* VB1T  = (unsigned short*)(wgt + 1888 * 1024);    // 32KB
    float*          CB0   = (float*)(wgt + 1920 * 1024);             // 1KB [ab0_b|vb0_b]

    float* out   = (float*)d_out;
    float* outre = out + (size_t)NTB * 9;
    float* outim = outre + LD * BB * PD;

    // ---- weight prep ----
    prep_k<<<512, 256, 0, stream>>>(B_re, B_im, C_re, C_im, Lre, Lim, lstep, BBART, CCATT);
    tcvt_k<<<256, 256, 0, stream>>>(enc0_W, E0T, 512, 128);
    tcvt_k<<<128, 256, 0, stream>>>(enc1_W, E1T, 128, 256);
    tcvt4_k<<<1024, 256, 0, stream>>>(glu_W, GLUT);
    tcvt_k<<<128, 256, 0, stream>>>(ab0_W, AB0VT, 256, 128);                 // rows 0..127
    tcvt_k<<<128, 256, 0, stream>>>(vb0_W, AB0VT + 128 * 256, 256, 128);     // rows 128..255
    tcvt_k<<<64, 256, 0, stream>>>(ab1_W, AB1T, 128, 128);
    tcvt_k<<<64, 256, 0, stream>>>(vb1_W, VB1T, 128, 128);
    catb_k<<<1, 256, 0, stream>>>(ab0_b, vb0_b, CB0);

    // ---- encoder ----
    mgemm_obs<<<1024, 256, 0, stream>>>(obs, E0T, U1, enc0_b);
    // enc1 fused: X = leaky(U1@E1+b), U = LN_0(X)
    mgemm2<0, 4, 4><<<1024, 512, 0, stream>>>(U1, E1T, 128, enc1_b, nsc, nbi, nullptr, X, U, 1);

    // ---- S5 layers ----
    for (int l = 0; l < LD; ++l) {
        mgemm2<1, 4, 8><<<1024, 512, 0, stream>>>(U, BBART + (size_t)l * 65536, 256,
                                               nullptr, nullptr, nullptr, nullptr, nullptr, BU, 0);
        scan2_k<<<512, 512, 0, stream>>>(BU, XS, dones, hre + l * BB * PD, him + l * BB * PD,
                                         Lre + l * PD, Lim + l * PD, lstep + l * PD,
                                         outre + l * BB * PD, outim + l * BB * PD);
        // z = gelu(LN_l(xs@C + D*u))   (in-place U: aux1=U read, U written)
        mgemm2<2, 4, 8><<<1024, 512, 0, stream>>>(XS, CCATT + (size_t)l * 65536, 256,
                                               Dv + l * HD, nsc + l * HD, nbi + l * HD, U, nullptr, U, 1);
        // x += z*sigmoid(z@W+b); u_next = LN_{l+1}(x)  (skip LN on last layer)
        const float* nsc2 = nsc + ((l + 1 < LD) ? (l + 1) * HD : 0);
        const float* nbi2 = nbi + ((l + 1 < LD) ? (l + 1) * HD : 0);
        mgemm2<3, 4, 8><<<1024, 512, 0, stream>>>(U, GLUT + (size_t)l * 65536, 256,
                                               glu_b + l * HD, nsc2, nbi2, U, X, U, (l + 1 < LD) ? 1 : 0);
    }

    // ---- heads ----
    // level 1 fused: [AM1|V1] = leaky(X @ [AB0|VB0] + [ab0_b|vb0_b])  (one X read)
    mgemm2<4, 4, 8><<<1024, 512, 0, stream>>>(X, AB0VT, 256, CB0, nullptr, nullptr, nullptr, nullptr, AMV1, 0);
    // level 2: read halves of AMV1 via LDA=256
    mgemm2<4, 2, 4><<<1024, 512, 0, stream>>>(AMV1, AB1T, 256, ab1_b, nullptr, nullptr, nullptr, nullptr, AM2, 0);
    mgemm2<4, 2, 4><<<1024, 512, 0, stream>>>(AMV1 + 128, VB1T, 256, vb1_b, nullptr, nullptr, nullptr, nullptr, V2, 0);
    head_k<<<NTB / 4, 256, 0, stream>>>(AM2, V2, adec_W, adec_b, log_std, vdec_W, vdec_b, out);
}

// Round 6
// 976.874 us; speedup vs baseline: 1.3505x; 1.3505x over previous
//
#include <hip/hip_runtime.h>
#include <math.h>

#define TT 512
#define BB 128
#define OBSD 512
#define HD 256
#define PD 128
#define LD 4
#define NTB (TT*BB)   // 65536

typedef __bf16 bf16x8 __attribute__((ext_vector_type(8)));
typedef float  f32x4  __attribute__((ext_vector_type(4)));

__device__ __forceinline__ float bf2f(unsigned short u) {
    return __uint_as_float(((unsigned)u) << 16);
}
__device__ __forceinline__ unsigned short f2bf(float f) {
    unsigned u = __float_as_uint(f);
    unsigned r = (u + 0x7FFFu + ((u >> 16) & 1u)) >> 16;
    return (unsigned short)r;
}
__device__ __forceinline__ float gelu_f(float x) {
    float x3 = x * x * x;
    return 0.5f * x * (1.f + tanhf(0.7978845608028654f * (x + 0.044715f * x3)));
}

// ====== Fused GEMM, tile 128 x (NJ*64), 512 threads (8 waves, 2M x 4N) ======
// m233 lesson: 2-phase cost/K-step = fixed(stage+vmcnt+barrier) + MFMA.
// R1/R4 tiles ran 8 MFMA/wave/step -> overhead-dominated. BM=128 doubles
// MFMA/wave/step to 16 (acc[4][NJ]) at the same fixed overhead.
// Double-buffered LDS, counted vmcnt (R1-proven schedule).
// acc[mi][nj][r] = C[row = wm*64+mi*16+(lane&15)][col = wn*NJ*16+nj*16+quad*4+r]
// MODE 0 (enc1): x = leaky(acc+bias);  write X; u = LN(x)           -> U
// MODE 1 (Bu):   write bf(acc)                                      -> U
// MODE 2 (ys):   v = acc + bias[c]*aux1; z = gelu(LN(v))            -> U
// MODE 3 (GLU):  x = Xold + aux1*sigmoid(acc+bias); write X; LN->U if wU
// MODE 4 (head): leaky(acc+bias)                                    -> U
template<int MODE, int NJ, int NK>
__global__ __launch_bounds__(512) void mgemm2(
    const unsigned short* __restrict__ A, const unsigned short* __restrict__ BT,
    int LDA, const float* __restrict__ bias,
    const float* __restrict__ lnsc, const float* __restrict__ lnbi,
    const unsigned short* __restrict__ aux1, unsigned short* Xio,
    unsigned short* __restrict__ U, int wU)
{
    constexpr int K = NK * 32;           // B^T leading dim (compile-time)
    constexpr int LPS = 1 + NJ / 2;      // loads per lane per stage
    const int N = NJ * 64;
    __shared__ unsigned short smA[2][128 * 32];      // 16KB
    __shared__ unsigned short smB[2][NJ * 64 * 32];  // NJ=4: 32KB
    // red only used AFTER the K-loop; alias onto smA ([128][4] float2 = 4KB)
    float2 (*red)[4] = reinterpret_cast<float2(*)[4]>(&smA[0][0]);
    int tid = threadIdx.x;
    int lane = tid & 63, w = tid >> 6;   // w in [0,8)
    int wm = w >> 2, wn = w & 3;         // 2M x 4N wave grid
    int m16 = lane & 15, quad = lane >> 4;
    int m0 = blockIdx.x * 128;

    f32x4 acc[4][NJ] = {};

    auto stage = [&](int bu, int kt) {
        int k0 = kt << 5;
        // A: 128x32 bf16 = 8KB -> 1 x 16B per thread
        {
            int r = tid >> 2, kq = (tid & 3) * 8;
            const unsigned short* g = A + (size_t)(m0 + r) * LDA + k0 + kq;
            __builtin_amdgcn_global_load_lds(
                (const __attribute__((address_space(1))) void*)g,
                (__attribute__((address_space(3))) void*)(&smA[bu][0] + tid * 8), 16, 0, 0);
        }
        // B: (NJ*64)x32 bf16 -> NJ/2 x 16B per thread
#pragma unroll
        for (int p = 0; p < NJ / 2; ++p) {
            int idx = p * 512 + tid;
            int r = idx >> 2, kq = (idx & 3) * 8;
            const unsigned short* g = BT + (size_t)r * K + k0 + kq;
            __builtin_amdgcn_global_load_lds(
                (const __attribute__((address_space(1))) void*)g,
                (__attribute__((address_space(3))) void*)(&smB[bu][0] + idx * 8), 16, 0, 0);
        }
    };

    int nk = NK;
    stage(0, 0);
    for (int t = 0; t < nk; ++t) {
        int cur = t & 1;
        if (t + 1 < nk) {
            stage(cur ^ 1, t + 1);
            // wait for tile t's LPS loads; tile t+1's stay in flight
            asm volatile("s_waitcnt vmcnt(%0)" :: "i"(LPS) : "memory");
        } else {
            asm volatile("s_waitcnt vmcnt(0)" ::: "memory");
        }
        __builtin_amdgcn_s_barrier();            // tile-t loads visible to all
        __builtin_amdgcn_sched_barrier(0);       // pin ds_reads below barrier
        bf16x8 af[4], bfr[NJ];
#pragma unroll
        for (int mi = 0; mi < 4; ++mi)
            af[mi] = *(const bf16x8*)(&smA[cur][0] + (wm * 64 + mi * 16 + m16) * 32 + quad * 8);
#pragma unroll
        for (int nj = 0; nj < NJ; ++nj)
            bfr[nj] = *(const bf16x8*)(&smB[cur][0] + (wn * NJ * 16 + nj * 16 + m16) * 32 + quad * 8);
#pragma unroll
        for (int mi = 0; mi < 4; ++mi)
#pragma unroll
            for (int nj = 0; nj < NJ; ++nj)
                acc[mi][nj] = __builtin_amdgcn_mfma_f32_16x16x32_bf16(
                    bfr[nj], af[mi], acc[mi][nj], 0, 0, 0);   // transposed: C^T
        __builtin_amdgcn_sched_barrier(0);       // pin reads above barrier
        __builtin_amdgcn_s_barrier();            // cur buf free for restage
    }

    int colb = wn * (NJ * 16) + quad * 4;    // + nj*16

    if (MODE == 1) {
#pragma unroll
        for (int mi = 0; mi < 4; ++mi) {
            size_t rowb = (size_t)(m0 + wm * 64 + mi * 16 + m16) * N;
#pragma unroll
            for (int nj = 0; nj < NJ; ++nj) {
                ushort4 o = { f2bf(acc[mi][nj][0]), f2bf(acc[mi][nj][1]),
                              f2bf(acc[mi][nj][2]), f2bf(acc[mi][nj][3]) };
                *(ushort4*)(U + rowb + colb + nj * 16) = o;
            }
        }
        return;
    }

    // ---- phase 1: transform acc -> v, write X/U, accumulate row stats ----
#pragma unroll
    for (int mi = 0; mi < 4; ++mi) {
        int row_l = wm * 64 + mi * 16 + m16;
        size_t rowb = (size_t)(m0 + row_l) * N;
        float s = 0.f, q = 0.f;
#pragma unroll
        for (int nj = 0; nj < NJ; ++nj) {
            float4 bn = *(const float4*)(bias + colb + nj * 16);
            ushort4 a1, xo;
            if (MODE == 2 || MODE == 3) a1 = *(const ushort4*)(aux1 + rowb + colb + nj * 16);
            if (MODE == 3)              xo = *(const ushort4*)(Xio + rowb + colb + nj * 16);
            float vv[4];
#pragma unroll
            for (int r = 0; r < 4; ++r) {
                float v = acc[mi][nj][r];
                float bv = (r == 0) ? bn.x : (r == 1) ? bn.y : (r == 2) ? bn.z : bn.w;
                if (MODE == 0 || MODE == 4) {
                    v += bv; v = v > 0.f ? v : 0.01f * v;
                } else if (MODE == 2) {
                    float u = bf2f(r == 0 ? a1.x : r == 1 ? a1.y : r == 2 ? a1.z : a1.w);
                    v += bv * u;
                } else if (MODE == 3) {
                    float zz = bf2f(r == 0 ? a1.x : r == 1 ? a1.y : r == 2 ? a1.z : a1.w);
                    float xx = bf2f(r == 0 ? xo.x : r == 1 ? xo.y : r == 2 ? xo.z : xo.w);
                    float sg = 1.f / (1.f + expf(-(v + bv)));
                    v = xx + zz * sg;
                }
                vv[r] = v;
                acc[mi][nj][r] = v;
                s += v; q += v * v;
            }
            if (MODE == 0 || MODE == 3) {
                ushort4 o = { f2bf(vv[0]), f2bf(vv[1]), f2bf(vv[2]), f2bf(vv[3]) };
                *(ushort4*)(Xio + rowb + colb + nj * 16) = o;
            } else if (MODE == 4) {
                ushort4 o = { f2bf(vv[0]), f2bf(vv[1]), f2bf(vv[2]), f2bf(vv[3]) };
                *(ushort4*)(U + rowb + colb + nj * 16) = o;
            }
        }
        if (MODE != 4 && (MODE != 3 || wU)) {
            s += __shfl_xor(s, 16); q += __shfl_xor(q, 16);
            s += __shfl_xor(s, 32); q += __shfl_xor(q, 32);
            if (quad == 0) red[row_l][wn] = float2{s, q};
        }
    }
    if (MODE == 4 || (MODE == 3 && !wU)) return;
    __syncthreads();

    // ---- phase 2: finalize LN, write U ----
#pragma unroll
    for (int mi = 0; mi < 4; ++mi) {
        int row_l = wm * 64 + mi * 16 + m16;
        float2 t0 = red[row_l][0], t1 = red[row_l][1], t2 = red[row_l][2], t3 = red[row_l][3];
        float S = t0.x + t1.x + t2.x + t3.x;
        float Q = t0.y + t1.y + t2.y + t3.y;
        float mu = S * (1.f / 256.f);
        float var = Q * (1.f / 256.f) - mu * mu;
        float rstd = rsqrtf(var + 1e-6f);
        size_t rowb = (size_t)(m0 + row_l) * N;
#pragma unroll
        for (int nj = 0; nj < NJ; ++nj) {
            float4 ls = *(const float4*)(lnsc + colb + nj * 16);
            float4 lb = *(const float4*)(lnbi + colb + nj * 16);
            float o[4];
#pragma unroll
            for (int r = 0; r < 4; ++r) {
                float sc = (r == 0) ? ls.x : (r == 1) ? ls.y : (r == 2) ? ls.z : ls.w;
                float bi = (r == 0) ? lb.x : (r == 1) ? lb.y : (r == 2) ? lb.z : lb.w;
                float v = (acc[mi][nj][r] - mu) * rstd * sc + bi;
                if (MODE == 2) v = gelu_f(v);
                o[r] = v;
            }
            ushort4 ov = { f2bf(o[0]), f2bf(o[1]), f2bf(o[2]), f2bf(o[3]) };
            *(ushort4*)(U + rowb + colb + nj * 16) = ov;
        }
    }
}

// ======= enc0: A f32 (obs), staged to bf16 LDS in VGPRs; tile 64x128 ========
__global__ __launch_bounds__(256) void mgemm_obs(
    const float* __restrict__ A, const unsigned short* __restrict__ BT,
    unsigned short* __restrict__ U, const float* __restrict__ bias)
{
    const int K = 512, NJ = 2, N = 128;
    __shared__ unsigned short smA[64 * 32];
    __shared__ unsigned short smB[NJ * 64 * 32];
    int tid = threadIdx.x;
    int lane = tid & 63, w = tid >> 6;
    int m16 = lane & 15, quad = lane >> 4;
    int m0 = blockIdx.x * 64;

    f32x4 acc[4][NJ] = {};
    for (int k0 = 0; k0 < K; k0 += 32) {
#pragma unroll
        for (int p = 0; p < 2; ++p) {
            int idx = p * 256 + tid;
            int r = idx >> 3, kq = (idx & 7) * 4;
            float4 v = *(const float4*)(A + (size_t)(m0 + r) * K + k0 + kq);
            ushort4 o = { f2bf(v.x), f2bf(v.y), f2bf(v.z), f2bf(v.w) };
            *(ushort4*)(smA + r * 32 + kq) = o;
        }
#pragma unroll
        for (int p = 0; p < NJ; ++p) {
            const unsigned short* g = BT + (size_t)(p * 64 + (tid >> 2)) * K + k0 + (tid & 3) * 8;
            unsigned short* l = smB + p * 2048 + tid * 8;
            __builtin_amdgcn_global_load_lds(
                (const __attribute__((address_space(1))) void*)g,
                (__attribute__((address_space(3))) void*)l, 16, 0, 0);
        }
        __syncthreads();
        bf16x8 af[4], bfr[NJ];
#pragma unroll
        for (int mi = 0; mi < 4; ++mi)
            af[mi] = *(const bf16x8*)(smA + (mi * 16 + m16) * 32 + quad * 8);
#pragma unroll
        for (int nj = 0; nj < NJ; ++nj)
            bfr[nj] = *(const bf16x8*)(smB + (w * NJ * 16 + nj * 16 + m16) * 32 + quad * 8);
#pragma unroll
        for (int mi = 0; mi < 4; ++mi)
#pragma unroll
            for (int nj = 0; nj < NJ; ++nj)
                acc[mi][nj] = __builtin_amdgcn_mfma_f32_16x16x32_bf16(
                    bfr[nj], af[mi], acc[mi][nj], 0, 0, 0);
        __syncthreads();
    }
    int colb = w * NJ * 16 + quad * 4;
#pragma unroll
    for (int mi = 0; mi < 4; ++mi) {
        size_t rowb = (size_t)(m0 + mi * 16 + m16) * N;
#pragma unroll
        for (int nj = 0; nj < NJ; ++nj) {
            float4 bv = *(const float4*)(bias + colb + nj * 16);
            float v0 = acc[mi][nj][0] + bv.x; v0 = v0 > 0.f ? v0 : 0.01f * v0;
            float v1 = acc[mi][nj][1] + bv.y; v1 = v1 > 0.f ? v1 : 0.01f * v1;
            float v2 = acc[mi][nj][2] + bv.z; v2 = v2 > 0.f ? v2 : 0.01f * v2;
            float v3 = acc[mi][nj][3] + bv.w; v3 = v3 > 0.f ? v3 : 0.01f * v3;
            ushort4 o = { f2bf(v0), f2bf(v1), f2bf(v2), f2bf(v3) };
            *(ushort4*)(U + rowb + colb + nj * 16) = o;
        }
    }
}

// ------------- Chunk-parallel scan: 512 blocks (B x 4 p-phases) -------------
__global__ __launch_bounds__(512) void scan2_k(
    const unsigned short* __restrict__ bu, unsigned short* __restrict__ xs,
    const float* __restrict__ dones,
    const float* __restrict__ h0re, const float* __restrict__ h0im,
    const float* __restrict__ lamre, const float* __restrict__ lamim,
    const float* __restrict__ lstep,
    float* __restrict__ outre, float* __restrict__ outim)
{
    __shared__ float sdone[TT];
    __shared__ float4 ssum[16][32];
    __shared__ float2 shin[16][32];
    int tid = threadIdx.x;
    int b  = blockIdx.x >> 2;
    int ph = blockIdx.x & 3;
    int chunk = tid >> 5, pl = tid & 31;
    int p = ph * 32 + pl;
    sdone[tid] = dones[tid * BB + b];
    float lr = lamre[p], li = lamim[p];
    float st = expf(lstep[p]);
    float er = expf(lr * st);
    float ar = er * cosf(li * st);
    float ai = er * sinf(li * st);
    __syncthreads();

    int t0 = chunk * 32;
    unsigned buf[32];
    float Ar = 1.f, Ai = 0.f, br = 0.f, bi = 0.f;
#pragma unroll
    for (int j = 0; j < 32; ++j) {
        size_t off = ((size_t)(t0 + j) * BB + b) * 256 + 2 * p;
        unsigned v = *(const unsigned*)(bu + off);
        buf[j] = v;
        float bur = bf2f((unsigned short)(v & 0xFFFFu));
        float bui = bf2f((unsigned short)(v >> 16));
        if (sdone[t0 + j] != 0.f) {
            Ar = 0.f; Ai = 0.f; br = bur; bi = bui;
        } else {
            float nAr = ar * Ar - ai * Ai;
            float nAi = ar * Ai + ai * Ar;
            float nbr = fmaf(ar, br, fmaf(-ai, bi, bur));
            float nbi = fmaf(ar, bi, fmaf(ai, br, bui));
            Ar = nAr; Ai = nAi; br = nbr; bi = nbi;
        }
    }
    ssum[chunk][pl] = float4{Ar, Ai, br, bi};
    __syncthreads();
    if (tid < 32) {
        int gid = b * 128 + ph * 32 + tid;
        float hr = h0re[gid], hi = h0im[gid];
#pragma unroll
        for (int c = 0; c < 16; ++c) {
            shin[c][tid] = float2{hr, hi};
            float4 s = ssum[c][tid];
            float nhr = fmaf(s.x, hr, fmaf(-s.y, hi, s.z));
            float nhi = fmaf(s.x, hi, fmaf(s.y, hr, s.w));
            hr = nhr; hi = nhi;
        }
        outre[gid] = hr; outim[gid] = hi;
    }
    __syncthreads();
    float hr = shin[chunk][pl].x, hi = shin[chunk][pl].y;
#pragma unroll
    for (int j = 0; j < 32; ++j) {
        unsigned v = buf[j];
        float bur = bf2f((unsigned short)(v & 0xFFFFu));
        float bui = bf2f((unsigned short)(v >> 16));
        float nr, ni;
        if (sdone[t0 + j] != 0.f) { nr = bur; ni = bui; }
        else {
            nr = fmaf(ar, hr, fmaf(-ai, hi, bur));
            ni = fmaf(ar, hi, fmaf(ai, hr, bui));
        }
        hr = nr; hi = ni;
        size_t off = ((size_t)(t0 + j) * BB + b) * 256 + 2 * p;
        *(unsigned*)(xs + off) = ((unsigned)f2bf(ni) << 16) | f2bf(nr);
    }
}

// -- Precompute B_barT (interleaved n: 2p/2p+1) and CcatT (interleaved k) ----
__global__ __launch_bounds__(256) void prep_k(
    const float* __restrict__ Br, const float* __restrict__ Bi,
    const float* __restrict__ Cr, const float* __restrict__ Ci,
    const float* __restrict__ Lr, const float* __restrict__ Li,
    const float* __restrict__ ls, unsigned short* bbarT, unsigned short* ccatT)
{
    int gid = blockIdx.x * 256 + threadIdx.x;   // L*P*H = 131072
    int l = gid >> 15;
    int rem = gid & 32767;
    int p = rem >> 8;
    int h = rem & 255;
    float lr = Lr[l * PD + p], li = Li[l * PD + p];
    float st = expf(ls[l * PD + p]);
    float er = expf(lr * st);
    float lbr = er * cosf(li * st);
    float lbi = er * sinf(li * st);
    float nr = lbr - 1.f, ni = lbi;
    float den = lr * lr + li * li;
    float fr = (nr * lr + ni * li) / den;
    float fi = (ni * lr - nr * li) / den;
    float bre = Br[(size_t)(l * PD + p) * HD + h];
    float bim = Bi[(size_t)(l * PD + p) * HD + h];
    size_t lb = (size_t)l * 65536;
    bbarT[lb + (size_t)(2 * p) * 256 + h]     = f2bf(fr * bre - fi * bim);
    bbarT[lb + (size_t)(2 * p + 1) * 256 + h] = f2bf(fr * bim + fi * bre);
    float cre = Cr[(size_t)(l * HD + h) * PD + p];
    float cim = Ci[(size_t)(l * HD + h) * PD + p];
    ccatT[lb + (size_t)h * 256 + 2 * p]     = f2bf(2.f * cre);
    ccatT[lb + (size_t)h * 256 + 2 * p + 1] = f2bf(-2.f * cim);
}

// -------- transpose+convert: in f32 [K][N] -> out bf16 [N][K] ---------------
__global__ __launch_bounds__(256) void tcvt_k(const float* __restrict__ in,
    unsigned short* __restrict__ out, int K, int N)
{
    int gid = blockIdx.x * 256 + threadIdx.x;
    if (gid >= K * N) return;
    int k = gid / N, n = gid - k * N;
    out[(size_t)n * K + k] = f2bf(in[gid]);
}

// -------- 4x fused GLU transpose: in f32 [4][256][256] -> bf16 [4][256][256]^T
__global__ __launch_bounds__(256) void tcvt4_k(const float* __restrict__ in,
    unsigned short* __restrict__ out)
{
    int gid = blockIdx.x * 256 + threadIdx.x;   // 4*65536
    int l = gid >> 16;
    int rem = gid & 65535;
    int k = rem >> 8, n = rem & 255;
    out[(size_t)l * 65536 + (size_t)n * 256 + k] = f2bf(in[gid]);
}

// -------- concat two 128-f32 bias vectors into one 256-f32 ------------------
__global__ __launch_bounds__(256) void catb_k(const float* __restrict__ a,
    const float* __restrict__ b, float* __restrict__ out)
{
    int i = threadIdx.x;
    out[i] = (i < 128) ? a[i] : b[i - 128];
}

// ---------------- Final heads: wave per row -> out[row*9 + ...] -------------
__global__ __launch_bounds__(256) void head_k(
    const unsigned short* __restrict__ am2, const unsigned short* __restrict__ v2,
    const float* __restrict__ adW, const float* __restrict__ adb,
    const float* __restrict__ lstd,
    const float* __restrict__ vdW, const float* __restrict__ vdb,
    float* out)
{
    int wid = threadIdx.x >> 6, lane = threadIdx.x & 63;
    size_t row = (size_t)blockIdx.x * 4 + wid;
    float a1 = bf2f(am2[row * 128 + lane]);
    float a2 = bf2f(am2[row * 128 + 64 + lane]);
    float w1 = bf2f(v2[row * 128 + lane]);
    float w2 = bf2f(v2[row * 128 + 64 + lane]);
    float vals[5];
#pragma unroll
    for (int a = 0; a < 4; ++a)
        vals[a] = a1 * adW[lane * 4 + a] + a2 * adW[(lane + 64) * 4 + a];
    vals[4] = w1 * vdW[lane] + w2 * vdW[64 + lane];
#pragma unroll
    for (int off = 32; off; off >>= 1)
#pragma unroll
        for (int k = 0; k < 5; ++k) vals[k] += __shfl_xor(vals[k], off);
    if (lane == 0) {
        size_t o = row * 9;
#pragma unroll
        for (int a = 0; a < 4; ++a) out[o + a] = vals[a] + adb[a];
#pragma unroll
        for (int a = 0; a < 4; ++a) out[o + 4 + a] = expf(lstd[a]);
        out[o + 8] = vals[4] + vdb[0];
    }
}

extern "C" void kernel_launch(void* const* d_in, const int* in_sizes, int n_in,
                              void* d_out, int out_size, void* d_ws, size_t ws_size,
                              hipStream_t stream) {
    (void)in_sizes; (void)n_in; (void)out_size; (void)ws_size;
    const float* obs     = (const float*)d_in[0];
    const float* dones   = (const float*)d_in[1];
    const float* hre     = (const float*)d_in[2];
    const float* him     = (const float*)d_in[3];
    const float* enc0_W  = (const float*)d_in[4];
    const float* enc0_b  = (const float*)d_in[5];
    const float* enc1_W  = (const float*)d_in[6];
    const float* enc1_b  = (const float*)d_in[7];
    const float* nsc     = (const float*)d_in[8];
    const float* nbi     = (const float*)d_in[9];
    const float* Lre     = (const float*)d_in[10];
    const float* Lim     = (const float*)d_in[11];
    const float* B_re    = (const float*)d_in[12];
    const float* B_im    = (const float*)d_in[13];
    const float* C_re    = (const float*)d_in[14];
    const float* C_im    = (const float*)d_in[15];
    const float* Dv      = (const float*)d_in[16];
    const float* lstep   = (const float*)d_in[17];
    const float* glu_W   = (const float*)d_in[18];
    const float* glu_b   = (const float*)d_in[19];
    const float* ab0_W   = (const float*)d_in[20];
    const float* ab0_b   = (const float*)d_in[21];
    const float* ab1_W   = (const float*)d_in[22];
    const float* ab1_b   = (const float*)d_in[23];
    const float* adec_W  = (const float*)d_in[24];
    const float* adec_b  = (const float*)d_in[25];
    const float* log_std = (const float*)d_in[26];
    const float* vb0_W   = (const float*)d_in[27];
    const float* vb0_b   = (const float*)d_in[28];
    const float* vb1_W   = (const float*)d_in[29];
    const float* vb1_b   = (const float*)d_in[30];
    const float* vdec_W  = (const float*)d_in[31];
    const float* vdec_b  = (const float*)d_in[32];

    const size_t MB = (size_t)1 << 20;
    char* wsb = (char*)d_ws;
    unsigned short* XS    = (unsigned short*)(wsb);              // 32MB (per-layer xs)
    unsigned short* AMV1  = (unsigned short*)(wsb);              // 32MB (heads lvl1, after scans)
    unsigned short* AM2   = (unsigned short*)(wsb + 32 * MB);    // 16MB (heads)
    unsigned short* V2    = (unsigned short*)(wsb + 48 * MB);    // 16MB (heads)
    unsigned short* U1    = (unsigned short*)(wsb + 64 * MB);    // 16MB (enc0 out)
    unsigned short* X     = (unsigned short*)(wsb + 96 * MB);    // 32MB residual bf16
    unsigned short* U     = (unsigned short*)(wsb + 128 * MB);   // 32MB (u / z)
    unsigned short* BU    = (unsigned short*)(wsb + 160 * MB);   // 32MB (Bu)
    char* wgt = wsb + 192 * MB;
    unsigned short* BBART = (unsigned short*)(wgt);                  // 512KB
    unsigned short* CCATT = (unsigned short*)(wgt + 512 * 1024);     // 512KB
    unsigned short* GLUT  = (unsigned short*)(wgt + 1024 * 1024);    // 512KB
    unsigned short* E0T   = (unsigned short*)(wgt + 1536 * 1024);    // 128KB
    unsigned short* E1T   = (unsigned short*)(wgt + 1664 * 1024);    // 64KB
    unsigned short* AB0VT = (unsigned short*)(wgt + 1728 * 1024);    // 128KB [AB0T;VB0T]
    unsigned short* AB1T  = (unsigned short*)(wgt + 1856 * 1024);    // 32KB
    unsigned short* VB1T  = (unsigned short*)(wgt + 1888 * 1024);    // 32KB
    float*          CB0   = (float*)(wgt + 1920 * 1024);             // 1KB [ab0_b|vb0_b]

    float* out   = (float*)d_out;
    float* outre = out + (size_t)NTB * 9;
    float* outim = outre + LD * BB * PD;

    // ---- weight prep ----
    prep_k<<<512, 256, 0, stream>>>(B_re, B_im, C_re, C_im, Lre, Lim, lstep, BBART, CCATT);
    tcvt_k<<<256, 256, 0, stream>>>(enc0_W, E0T, 512, 128);
    tcvt_k<<<128, 256, 0, stream>>>(enc1_W, E1T, 128, 256);
    tcvt4_k<<<1024, 256, 0, stream>>>(glu_W, GLUT);
    tcvt_k<<<128, 256, 0, stream>>>(ab0_W, AB0VT, 256, 128);                 // rows 0..127
    tcvt_k<<<128, 256, 0, stream>>>(vb0_W, AB0VT + 128 * 256, 256, 128);     // rows 128..255
    tcvt_k<<<64, 256, 0, stream>>>(ab1_W, AB1T, 128, 128);
    tcvt_k<<<64, 256, 0, stream>>>(vb1_W, VB1T, 128, 128);
    catb_k<<<1, 256, 0, stream>>>(ab0_b, vb0_b, CB0);

    // ---- encoder ----
    mgemm_obs<<<1024, 256, 0, stream>>>(obs, E0T, U1, enc0_b);
    // enc1 fused: X = leaky(U1@E1+b), U = LN_0(X)
    mgemm2<0, 4, 4><<<512, 512, 0, stream>>>(U1, E1T, 128, enc1_b, nsc, nbi, nullptr, X, U, 1);

    // ---- S5 layers ----
    for (int l = 0; l < LD; ++l) {
        mgemm2<1, 4, 8><<<512, 512, 0, stream>>>(U, BBART + (size_t)l * 65536, 256,
                                               nullptr, nullptr, nullptr, nullptr, nullptr, BU, 0);
        scan2_k<<<512, 512, 0, stream>>>(BU, XS, dones, hre + l * BB * PD, him + l * BB * PD,
                                         Lre + l * PD, Lim + l * PD, lstep + l * PD,
                                         outre + l * BB * PD, outim + l * BB * PD);
        // z = gelu(LN_l(xs@C + D*u))   (in-place U: aux1=U read, U written)
        mgemm2<2, 4, 8><<<512, 512, 0, stream>>>(XS, CCATT + (size_t)l * 65536, 256,
                                               Dv + l * HD, nsc + l * HD, nbi + l * HD, U, nullptr, U, 1);
        // x += z*sigmoid(z@W+b); u_next = LN_{l+1}(x)  (skip LN on last layer)
        const float* nsc2 = nsc + ((l + 1 < LD) ? (l + 1) * HD : 0);
        const float* nbi2 = nbi + ((l + 1 < LD) ? (l + 1) * HD : 0);
        mgemm2<3, 4, 8><<<512, 512, 0, stream>>>(U, GLUT + (size_t)l * 65536, 256,
                                               glu_b + l * HD, nsc2, nbi2, U, X, U, (l + 1 < LD) ? 1 : 0);
    }

    // ---- heads ----
    // level 1 fused: [AM1|V1] = leaky(X @ [AB0|VB0] + [ab0_b|vb0_b])  (one X read)
    mgemm2<4, 4, 8><<<512, 512, 0, stream>>>(X, AB0VT, 256, CB0, nullptr, nullptr, nullptr, nullptr, AMV1, 0);
    // level 2: read halves of AMV1 via LDA=256
    mgemm2<4, 2, 4><<<512, 512, 0, stream>>>(AMV1, AB1T, 256, ab1_b, nullptr, nullptr, nullptr, nullptr, AM2, 0);
    mgemm2<4, 2, 4><<<512, 512, 0, stream>>>(AMV1 + 128, VB1T, 256, vb1_b, nullptr, nullptr, nullptr, nullptr, V2, 0);
    head_k<<<NTB / 4, 256, 0, stream>>>(AM2, V2, adec_W, adec_b, log_std, vdec_W, vdec_b, out);
}

// Round 7
// 872.424 us; speedup vs baseline: 1.5122x; 1.1197x over previous
//
#include <hip/hip_runtime.h>
#include <math.h>

#define TT 512
#define BB 128
#define OBSD 512
#define HD 256
#define PD 128
#define LD 4
#define NTB (TT*BB)   // 65536

typedef __bf16 bf16x8 __attribute__((ext_vector_type(8)));
typedef float  f32x4  __attribute__((ext_vector_type(4)));

__device__ __forceinline__ float bf2f(unsigned short u) {
    return __uint_as_float(((unsigned)u) << 16);
}
__device__ __forceinline__ unsigned short f2bf(float f) {
    unsigned u = __float_as_uint(f);
    unsigned r = (u + 0x7FFFu + ((u >> 16) & 1u)) >> 16;
    return (unsigned short)r;
}
__device__ __forceinline__ float gelu_f(float x) {
    float x3 = x * x * x;
    return 0.5f * x * (1.f + tanhf(0.7978845608028654f * (x + 0.044715f * x3)));
}

// ============ Fused GEMM, tile 64 x (NJ*64), 512 threads / 8 waves ==========
// (R4 structure, best measured: 960us) Triple-buffered LDS staging, depth-2
// prefetch, counted vmcnt. Uniform per-wave staging (2x4B A + NJW x16B B).
// acc[mi][nj][r] = C[row = mi*16+(lane&15)][col = w*NJW*16 + nj*16 + quad*4 + r]
// MODE 0 (enc1): x = leaky(acc+bias);  write X; u = LN(x)           -> U
// MODE 1 (Bu):   write bf(acc)                                      -> U
// MODE 2 (ys):   v = acc + bias[c]*aux1; z = gelu(LN(v))            -> U
// MODE 3 (GLU):  x = Xold + aux1*sigmoid(acc+bias); write X; LN->U if wU
template<int MODE, int NJ, int NK>
__global__ __launch_bounds__(512) void mgemm2(
    const unsigned short* __restrict__ A, const unsigned short* __restrict__ BT,
    int LDA, const float* __restrict__ bias,
    const float* __restrict__ lnsc, const float* __restrict__ lnbi,
    const unsigned short* __restrict__ aux1, unsigned short* Xio,
    unsigned short* __restrict__ U, int wU)
{
    constexpr int NJW = NJ / 2;          // 16-col tiles per wave
    constexpr int LPS = 2 + NJW;         // loads per wave-lane per stage
    constexpr int K = NK * 32;
    const int N = NJ * 64;
    __shared__ unsigned short smA[3 * 2048];        // 3 bufs x 64x32
    __shared__ unsigned short smB[3 * NJ * 2048];   // 3 bufs x (NJ*64)x32
    float2 (*red)[8] = reinterpret_cast<float2(*)[8]>(&smA[0]);
    int tid = threadIdx.x;
    int lane = tid & 63, w = tid >> 6;
    int m16 = lane & 15, quad = lane >> 4;
    int m0 = blockIdx.x * 64;

    f32x4 acc[4][NJW] = {};

    auto stage = [&](int slot, int kt) {
        int k0 = kt << 5;
#pragma unroll
        for (int j = 0; j < 2; ++j) {
            int chunk = w * 2 + j;
            int e = chunk * 128 + lane * 2;
            int row = e >> 5, kb = e & 31;
            const unsigned short* g = A + (size_t)(m0 + row) * LDA + k0 + kb;
            __builtin_amdgcn_global_load_lds(
                (const __attribute__((address_space(1))) void*)g,
                (__attribute__((address_space(3))) void*)(smA + slot * 2048 + e), 4, 0, 0);
        }
#pragma unroll
        for (int j = 0; j < NJW; ++j) {
            int chunk = w * NJW + j;
            int e = chunk * 512 + lane * 8;
            int p = e >> 11, r = (e >> 5) & 63, kq = e & 31;
            const unsigned short* g = BT + (size_t)(p * 64 + r) * K + k0 + kq;
            __builtin_amdgcn_global_load_lds(
                (const __attribute__((address_space(1))) void*)g,
                (__attribute__((address_space(3))) void*)(smB + slot * NJ * 2048 + e), 16, 0, 0);
        }
    };

    int nk = NK;
    stage(0, 0);
    stage(1, 1);
    int cur = 0, nxt = 2;
    for (int t = 0; t < nk; ++t) {
        int rem = nk - 1 - t;
        if (rem >= 2) {
            stage(nxt, t + 2);
            nxt = (nxt == 2) ? 0 : nxt + 1;
            asm volatile("s_waitcnt vmcnt(%0)" :: "i"(2 * LPS) : "memory");
        } else if (rem == 1) {
            asm volatile("s_waitcnt vmcnt(%0)" :: "i"(LPS) : "memory");
        } else {
            asm volatile("s_waitcnt vmcnt(0)" ::: "memory");
        }
        __builtin_amdgcn_s_barrier();
        __builtin_amdgcn_sched_barrier(0);
        bf16x8 af[4], bfr[NJW];
#pragma unroll
        for (int mi = 0; mi < 4; ++mi)
            af[mi] = *(const bf16x8*)(smA + cur * 2048 + (mi * 16 + m16) * 32 + quad * 8);
#pragma unroll
        for (int nj = 0; nj < NJW; ++nj)
            bfr[nj] = *(const bf16x8*)(smB + cur * NJ * 2048 + (w * NJW + nj) * 512 + m16 * 32 + quad * 8);
#pragma unroll
        for (int mi = 0; mi < 4; ++mi)
#pragma unroll
            for (int nj = 0; nj < NJW; ++nj)
                acc[mi][nj] = __builtin_amdgcn_mfma_f32_16x16x32_bf16(
                    bfr[nj], af[mi], acc[mi][nj], 0, 0, 0);   // transposed: C^T
        __builtin_amdgcn_sched_barrier(0);
        __builtin_amdgcn_s_barrier();
        cur = (cur == 2) ? 0 : cur + 1;
    }

    int colb = w * (NJW * 16) + quad * 4;

    if (MODE == 1) {
#pragma unroll
        for (int mi = 0; mi < 4; ++mi) {
            size_t rowb = (size_t)(m0 + mi * 16 + m16) * N;
#pragma unroll
            for (int nj = 0; nj < NJW; ++nj) {
                ushort4 o = { f2bf(acc[mi][nj][0]), f2bf(acc[mi][nj][1]),
                              f2bf(acc[mi][nj][2]), f2bf(acc[mi][nj][3]) };
                *(ushort4*)(U + rowb + colb + nj * 16) = o;
            }
        }
        return;
    }

    // ---- phase 1: transform acc -> v, write X/U, accumulate row stats ----
#pragma unroll
    for (int mi = 0; mi < 4; ++mi) {
        size_t rowb = (size_t)(m0 + mi * 16 + m16) * N;
        float s = 0.f, q = 0.f;
#pragma unroll
        for (int nj = 0; nj < NJW; ++nj) {
            float4 bn = *(const float4*)(bias + colb + nj * 16);
            ushort4 a1, xo;
            if (MODE == 2 || MODE == 3) a1 = *(const ushort4*)(aux1 + rowb + colb + nj * 16);
            if (MODE == 3)              xo = *(const ushort4*)(Xio + rowb + colb + nj * 16);
            float vv[4];
#pragma unroll
            for (int r = 0; r < 4; ++r) {
                float v = acc[mi][nj][r];
                float bv = (r == 0) ? bn.x : (r == 1) ? bn.y : (r == 2) ? bn.z : bn.w;
                if (MODE == 0) {
                    v += bv; v = v > 0.f ? v : 0.01f * v;
                } else if (MODE == 2) {
                    float u = bf2f(r == 0 ? a1.x : r == 1 ? a1.y : r == 2 ? a1.z : a1.w);
                    v += bv * u;
                } else if (MODE == 3) {
                    float zz = bf2f(r == 0 ? a1.x : r == 1 ? a1.y : r == 2 ? a1.z : a1.w);
                    float xx = bf2f(r == 0 ? xo.x : r == 1 ? xo.y : r == 2 ? xo.z : xo.w);
                    float sg = 1.f / (1.f + expf(-(v + bv)));
                    v = xx + zz * sg;
                }
                vv[r] = v;
                acc[mi][nj][r] = v;
                s += v; q += v * v;
            }
            if (MODE == 0 || MODE == 3) {
                ushort4 o = { f2bf(vv[0]), f2bf(vv[1]), f2bf(vv[2]), f2bf(vv[3]) };
                *(ushort4*)(Xio + rowb + colb + nj * 16) = o;
            }
        }
        if (MODE != 3 || wU) {
            s += __shfl_xor(s, 16); q += __shfl_xor(q, 16);
            s += __shfl_xor(s, 32); q += __shfl_xor(q, 32);
            if (quad == 0) red[mi * 16 + m16][w] = float2{s, q};
        }
    }
    if (MODE == 3 && !wU) return;
    __syncthreads();

    // ---- phase 2: finalize LN, write U ----
#pragma unroll
    for (int mi = 0; mi < 4; ++mi) {
        int row_l = mi * 16 + m16;
        float S = 0.f, Q = 0.f;
#pragma unroll
        for (int ww = 0; ww < 8; ++ww) {
            float2 tv = red[row_l][ww];
            S += tv.x; Q += tv.y;
        }
        float mu = S * (1.f / 256.f);
        float var = Q * (1.f / 256.f) - mu * mu;
        float rstd = rsqrtf(var + 1e-6f);
        size_t rowb = (size_t)(m0 + row_l) * N;
#pragma unroll
        for (int nj = 0; nj < NJW; ++nj) {
            float4 ls = *(const float4*)(lnsc + colb + nj * 16);
            float4 lb = *(const float4*)(lnbi + colb + nj * 16);
            float o[4];
#pragma unroll
            for (int r = 0; r < 4; ++r) {
                float sc = (r == 0) ? ls.x : (r == 1) ? ls.y : (r == 2) ? ls.z : ls.w;
                float bi = (r == 0) ? lb.x : (r == 1) ? lb.y : (r == 2) ? lb.z : lb.w;
                float v = (acc[mi][nj][r] - mu) * rstd * sc + bi;
                if (MODE == 2) v = gelu_f(v);
                o[r] = v;
            }
            ushort4 ov = { f2bf(o[0]), f2bf(o[1]), f2bf(o[2]), f2bf(o[3]) };
            *(ushort4*)(U + rowb + colb + nj * 16) = ov;
        }
    }
}

// ====== GLU + Bu fused: x+=z*sig(z@W+b); u'=LN(x) -> U & LDS; BU=u'@Bbar ====
// u_next never round-trips HBM for the Bu GEMM (saves 32MB + 1 dispatch/layer).
// LDS: smA 8KB + smB 32KB + zbuf 33KB = 73KB -> 2 blocks/CU.
__global__ __launch_bounds__(512) void glu_bu_k(
    const unsigned short* __restrict__ Z,     // z (A and aux)
    const unsigned short* __restrict__ GT,    // GLU^T [256][256]
    const unsigned short* __restrict__ BT2,   // BbarT_{l+1} [256][256]
    const float* __restrict__ glub,
    const float* __restrict__ ns2, const float* __restrict__ nb2,
    unsigned short* __restrict__ Xio,
    unsigned short* __restrict__ Uo,
    unsigned short* __restrict__ BUo)
{
    const int N = 256;
    __shared__ unsigned short smA[2 * 2048];
    __shared__ unsigned short smB[2 * 8192];
    __shared__ unsigned short zbuf[64 * 264];
    float2 (*red)[8] = reinterpret_cast<float2(*)[8]>(&smA[0]);
    int tid = threadIdx.x;
    int lane = tid & 63, w = tid >> 6;
    int m16 = lane & 15, quad = lane >> 4;
    int m0 = blockIdx.x * 64;
    int colb = w * 32 + quad * 4;

    f32x4 acc[4][2] = {};

    auto stage1 = [&](int slot, int kt) {
        int k0 = kt << 5;
#pragma unroll
        for (int j = 0; j < 2; ++j) {
            int e = (w * 2 + j) * 128 + lane * 2;
            int row = e >> 5, kb = e & 31;
            const unsigned short* g = Z + (size_t)(m0 + row) * 256 + k0 + kb;
            __builtin_amdgcn_global_load_lds(
                (const __attribute__((address_space(1))) void*)g,
                (__attribute__((address_space(3))) void*)(smA + slot * 2048 + e), 4, 0, 0);
        }
#pragma unroll
        for (int j = 0; j < 2; ++j) {
            int e = (w * 2 + j) * 512 + lane * 8;
            int p = e >> 11, r = (e >> 5) & 63, kq = e & 31;
            const unsigned short* g = GT + (size_t)(p * 64 + r) * 256 + k0 + kq;
            __builtin_amdgcn_global_load_lds(
                (const __attribute__((address_space(1))) void*)g,
                (__attribute__((address_space(3))) void*)(smB + slot * 8192 + e), 16, 0, 0);
        }
    };
    auto stage2 = [&](int slot, int kt) {
        int k0 = kt << 5;
#pragma unroll
        for (int j = 0; j < 2; ++j) {
            int e = (w * 2 + j) * 512 + lane * 8;
            int p = e >> 11, r = (e >> 5) & 63, kq = e & 31;
            const unsigned short* g = BT2 + (size_t)(p * 64 + r) * 256 + k0 + kq;
            __builtin_amdgcn_global_load_lds(
                (const __attribute__((address_space(1))) void*)g,
                (__attribute__((address_space(3))) void*)(smB + slot * 8192 + e), 16, 0, 0);
        }
    };

    stage1(0, 0);
    for (int t = 0; t < 8; ++t) {
        int cur = t & 1;
        if (t + 1 < 8) {
            stage1(cur ^ 1, t + 1);
            asm volatile("s_waitcnt vmcnt(4)" ::: "memory");
        } else {
            asm volatile("s_waitcnt vmcnt(0)" ::: "memory");
        }
        __builtin_amdgcn_s_barrier();
        __builtin_amdgcn_sched_barrier(0);
        bf16x8 af[4], bfr[2];
#pragma unroll
        for (int mi = 0; mi < 4; ++mi)
            af[mi] = *(const bf16x8*)(smA + cur * 2048 + (mi * 16 + m16) * 32 + quad * 8);
#pragma unroll
        for (int nj = 0; nj < 2; ++nj)
            bfr[nj] = *(const bf16x8*)(smB + cur * 8192 + (w * 2 + nj) * 512 + m16 * 32 + quad * 8);
#pragma unroll
        for (int mi = 0; mi < 4; ++mi)
#pragma unroll
            for (int nj = 0; nj < 2; ++nj)
                acc[mi][nj] = __builtin_amdgcn_mfma_f32_16x16x32_bf16(
                    bfr[nj], af[mi], acc[mi][nj], 0, 0, 0);
        __builtin_amdgcn_sched_barrier(0);
        __builtin_amdgcn_s_barrier();
    }

    // prefetch first BbarT tile under the epilogue (T14 issue-early)
    stage2(0, 0);

    // ---- epilogue: x_new = x + z*sigmoid(acc+glub); LN stats ----
#pragma unroll
    for (int mi = 0; mi < 4; ++mi) {
        int row_l = mi * 16 + m16;
        size_t rowb = (size_t)(m0 + row_l) * N;
        float s = 0.f, q = 0.f;
#pragma unroll
        for (int nj = 0; nj < 2; ++nj) {
            float4 gb = *(const float4*)(glub + colb + nj * 16);
            ushort4 a1 = *(const ushort4*)(Z + rowb + colb + nj * 16);
            ushort4 xo = *(const ushort4*)(Xio + rowb + colb + nj * 16);
            float vv[4];
#pragma unroll
            for (int r = 0; r < 4; ++r) {
                float v = acc[mi][nj][r];
                float bv = (r == 0) ? gb.x : (r == 1) ? gb.y : (r == 2) ? gb.z : gb.w;
                float zz = bf2f(r == 0 ? a1.x : r == 1 ? a1.y : r == 2 ? a1.z : a1.w);
                float xx = bf2f(r == 0 ? xo.x : r == 1 ? xo.y : r == 2 ? xo.z : xo.w);
                float sg = 1.f / (1.f + expf(-(v + bv)));
                v = xx + zz * sg;
                vv[r] = v;
                acc[mi][nj][r] = v;
                s += v; q += v * v;
            }
            ushort4 o = { f2bf(vv[0]), f2bf(vv[1]), f2bf(vv[2]), f2bf(vv[3]) };
            *(ushort4*)(Xio + rowb + colb + nj * 16) = o;
        }
        s += __shfl_xor(s, 16); q += __shfl_xor(q, 16);
        s += __shfl_xor(s, 32); q += __shfl_xor(q, 32);
        if (quad == 0) red[row_l][w] = float2{s, q};
    }
    __syncthreads();

    // ---- LN2 -> Uo (global, needed as next layer's u) + zbuf ----
#pragma unroll
    for (int mi = 0; mi < 4; ++mi) {
        int row_l = mi * 16 + m16;
        float S = 0.f, Q = 0.f;
#pragma unroll
        for (int ww = 0; ww < 8; ++ww) { float2 tv = red[row_l][ww]; S += tv.x; Q += tv.y; }
        float mu = S * (1.f / 256.f);
        float var = Q * (1.f / 256.f) - mu * mu;
        float rstd = rsqrtf(var + 1e-6f);
        size_t rowb = (size_t)(m0 + row_l) * N;
#pragma unroll
        for (int nj = 0; nj < 2; ++nj) {
            float4 ls = *(const float4*)(ns2 + colb + nj * 16);
            float4 lb = *(const float4*)(nb2 + colb + nj * 16);
            float o[4];
#pragma unroll
            for (int r = 0; r < 4; ++r) {
                float sc = (r == 0) ? ls.x : (r == 1) ? ls.y : (r == 2) ? ls.z : ls.w;
                float bi = (r == 0) ? lb.x : (r == 1) ? lb.y : (r == 2) ? lb.z : lb.w;
                o[r] = (acc[mi][nj][r] - mu) * rstd * sc + bi;
            }
            ushort4 ov = { f2bf(o[0]), f2bf(o[1]), f2bf(o[2]), f2bf(o[3]) };
            *(ushort4*)(Uo + rowb + colb + nj * 16) = ov;
            *(ushort4*)(zbuf + row_l * 264 + colb + nj * 16) = ov;
        }
    }
    __syncthreads();

    // ---- GEMM2: BU = u_next @ BbarT ----
    f32x4 acc2[4][2] = {};
    for (int t = 0; t < 8; ++t) {
        int cur = t & 1;
        if (t + 1 < 8) {
            stage2(cur ^ 1, t + 1);
            asm volatile("s_waitcnt vmcnt(2)" ::: "memory");
        } else {
            asm volatile("s_waitcnt vmcnt(0)" ::: "memory");
        }
        __builtin_amdgcn_s_barrier();
        __builtin_amdgcn_sched_barrier(0);
        bf16x8 af[4], bfr[2];
#pragma unroll
        for (int mi = 0; mi < 4; ++mi)
            af[mi] = *(const bf16x8*)(zbuf + (mi * 16 + m16) * 264 + t * 32 + quad * 8);
#pragma unroll
        for (int nj = 0; nj < 2; ++nj)
            bfr[nj] = *(const bf16x8*)(smB + cur * 8192 + (w * 2 + nj) * 512 + m16 * 32 + quad * 8);
#pragma unroll
        for (int mi = 0; mi < 4; ++mi)
#pragma unroll
            for (int nj = 0; nj < 2; ++nj)
                acc2[mi][nj] = __builtin_amdgcn_mfma_f32_16x16x32_bf16(
                    bfr[nj], af[mi], acc2[mi][nj], 0, 0, 0);
        __builtin_amdgcn_sched_barrier(0);
        __builtin_amdgcn_s_barrier();
    }
#pragma unroll
    for (int mi = 0; mi < 4; ++mi) {
        size_t rowb = (size_t)(m0 + mi * 16 + m16) * N;
#pragma unroll
        for (int nj = 0; nj < 2; ++nj) {
            ushort4 o = { f2bf(acc2[mi][nj][0]), f2bf(acc2[mi][nj][1]),
                          f2bf(acc2[mi][nj][2]), f2bf(acc2[mi][nj][3]) };
            *(ushort4*)(BUo + rowb + colb + nj * 16) = o;
        }
    }
}

// ====== Heads fully fused: X -> lvl1(LDS) -> lvl2(AM||V) -> decode -> out ===
// Eliminates AMV1/AM2/V2 round-trips (~128MB) and 3 dispatches.
__global__ __launch_bounds__(512) void head_fused_k(
    const unsigned short* __restrict__ Xp, const unsigned short* __restrict__ W0T,
    const float* __restrict__ cb0,
    const unsigned short* __restrict__ AB1T, const unsigned short* __restrict__ VB1T,
    const float* __restrict__ ab1b, const float* __restrict__ vb1b,
    const float* __restrict__ adW, const float* __restrict__ adb,
    const float* __restrict__ lstd,
    const float* __restrict__ vdW, const float* __restrict__ vdb,
    float* __restrict__ out)
{
    __shared__ unsigned short smA[2 * 2048];
    __shared__ unsigned short smB[2 * 8192];
    __shared__ unsigned short zbuf[64 * 264];
    float (*redh)[8][4] = reinterpret_cast<float(*)[8][4]>(&smA[0]);
    int tid = threadIdx.x;
    int lane = tid & 63, w = tid >> 6;
    int m16 = lane & 15, quad = lane >> 4;
    int m0 = blockIdx.x * 64;
    int colb = w * 32 + quad * 4;

    f32x4 acc[4][2] = {};

    auto stage1 = [&](int slot, int kt) {
        int k0 = kt << 5;
#pragma unroll
        for (int j = 0; j < 2; ++j) {
            int e = (w * 2 + j) * 128 + lane * 2;
            int row = e >> 5, kb = e & 31;
            const unsigned short* g = Xp + (size_t)(m0 + row) * 256 + k0 + kb;
            __builtin_amdgcn_global_load_lds(
                (const __attribute__((address_space(1))) void*)g,
                (__attribute__((address_space(3))) void*)(smA + slot * 2048 + e), 4, 0, 0);
        }
#pragma unroll
        for (int j = 0; j < 2; ++j) {
            int e = (w * 2 + j) * 512 + lane * 8;
            int p = e >> 11, r = (e >> 5) & 63, kq = e & 31;
            const unsigned short* g = W0T + (size_t)(p * 64 + r) * 256 + k0 + kq;
            __builtin_amdgcn_global_load_lds(
                (const __attribute__((address_space(1))) void*)g,
                (__attribute__((address_space(3))) void*)(smB + slot * 8192 + e), 16, 0, 0);
        }
    };
    auto stage2 = [&](int slot, int kt) {
        int k0 = kt << 5;
#pragma unroll
        for (int j = 0; j < 2; ++j) {
            int e = (w * 2 + j) * 512 + lane * 8;
            int r = e >> 5, kq = e & 31;
            const unsigned short* g = (r < 128)
                ? AB1T + (size_t)r * 128 + k0 + kq
                : VB1T + (size_t)(r - 128) * 128 + k0 + kq;
            __builtin_amdgcn_global_load_lds(
                (const __attribute__((address_space(1))) void*)g,
                (__attribute__((address_space(3))) void*)(smB + slot * 8192 + e), 16, 0, 0);
        }
    };

    // ---- lvl1: [AM1|V1] = leaky(X @ [AB0|VB0] + cb0) -> zbuf ----
    stage1(0, 0);
    for (int t = 0; t < 8; ++t) {
        int cur = t & 1;
        if (t + 1 < 8) {
            stage1(cur ^ 1, t + 1);
            asm volatile("s_waitcnt vmcnt(4)" ::: "memory");
        } else {
            asm volatile("s_waitcnt vmcnt(0)" ::: "memory");
        }
        __builtin_amdgcn_s_barrier();
        __builtin_amdgcn_sched_barrier(0);
        bf16x8 af[4], bfr[2];
#pragma unroll
        for (int mi = 0; mi < 4; ++mi)
            af[mi] = *(const bf16x8*)(smA + cur * 2048 + (mi * 16 + m16) * 32 + quad * 8);
#pragma unroll
        for (int nj = 0; nj < 2; ++nj)
            bfr[nj] = *(const bf16x8*)(smB + cur * 8192 + (w * 2 + nj) * 512 + m16 * 32 + quad * 8);
#pragma unroll
        for (int mi = 0; mi < 4; ++mi)
#pragma unroll
            for (int nj = 0; nj < 2; ++nj)
                acc[mi][nj] = __builtin_amdgcn_mfma_f32_16x16x32_bf16(
                    bfr[nj], af[mi], acc[mi][nj], 0, 0, 0);
        __builtin_amdgcn_sched_barrier(0);
        __builtin_amdgcn_s_barrier();
    }
    stage2(0, 0);   // prefetch first lvl2 weight tile under the epilogue
#pragma unroll
    for (int mi = 0; mi < 4; ++mi) {
        int row_l = mi * 16 + m16;
#pragma unroll
        for (int nj = 0; nj < 2; ++nj) {
            float4 bn = *(const float4*)(cb0 + colb + nj * 16);
            float v0 = acc[mi][nj][0] + bn.x; v0 = v0 > 0.f ? v0 : 0.01f * v0;
            float v1 = acc[mi][nj][1] + bn.y; v1 = v1 > 0.f ? v1 : 0.01f * v1;
            float v2 = acc[mi][nj][2] + bn.z; v2 = v2 > 0.f ? v2 : 0.01f * v2;
            float v3 = acc[mi][nj][3] + bn.w; v3 = v3 > 0.f ? v3 : 0.01f * v3;
            ushort4 o = { f2bf(v0), f2bf(v1), f2bf(v2), f2bf(v3) };
            *(ushort4*)(zbuf + row_l * 264 + colb + nj * 16) = o;
        }
    }
    __syncthreads();

    // ---- lvl2: waves 0-3 -> AM2 (AB1T), waves 4-7 -> V2 (VB1T); K=128 ----
    f32x4 acc2[4][2] = {};
    int abase = (w < 4) ? 0 : 128;
    for (int t = 0; t < 4; ++t) {
        int cur = t & 1;
        if (t + 1 < 4) {
            stage2(cur ^ 1, t + 1);
            asm volatile("s_waitcnt vmcnt(2)" ::: "memory");
        } else {
            asm volatile("s_waitcnt vmcnt(0)" ::: "memory");
        }
        __builtin_amdgcn_s_barrier();
        __builtin_amdgcn_sched_barrier(0);
        bf16x8 af[4], bfr[2];
#pragma unroll
        for (int mi = 0; mi < 4; ++mi)
            af[mi] = *(const bf16x8*)(zbuf + (mi * 16 + m16) * 264 + abase + t * 32 + quad * 8);
#pragma unroll
        for (int nj = 0; nj < 2; ++nj) {
            int rb = abase + (w & 3) * 32 + nj * 16 + m16;
            bfr[nj] = *(const bf16x8*)(smB + cur * 8192 + rb * 32 + quad * 8);
        }
#pragma unroll
        for (int mi = 0; mi < 4; ++mi)
#pragma unroll
            for (int nj = 0; nj < 2; ++nj)
                acc2[mi][nj] = __builtin_amdgcn_mfma_f32_16x16x32_bf16(
                    bfr[nj], af[mi], acc2[mi][nj], 0, 0, 0);
        __builtin_amdgcn_sched_barrier(0);
        __builtin_amdgcn_s_barrier();
    }

    // ---- decode: leaky(acc2+b1) dotted with adec/vdec, reduce over cols ----
    float pd[4][4] = {};
    float pv[4] = {0.f, 0.f, 0.f, 0.f};
#pragma unroll
    for (int nj = 0; nj < 2; ++nj)
#pragma unroll
        for (int r = 0; r < 4; ++r) {
            int c = (w & 3) * 32 + nj * 16 + quad * 4 + r;
            float bb = (w < 4) ? ab1b[c] : vb1b[c];
            float4 aw = {0.f, 0.f, 0.f, 0.f};
            float vw = 0.f;
            if (w < 4) aw = *(const float4*)(adW + c * 4);
            else       vw = vdW[c];
#pragma unroll
            for (int mi = 0; mi < 4; ++mi) {
                float v = acc2[mi][nj][r] + bb;
                v = v > 0.f ? v : 0.01f * v;
                if (w < 4) {
                    pd[mi][0] += v * aw.x; pd[mi][1] += v * aw.y;
                    pd[mi][2] += v * aw.z; pd[mi][3] += v * aw.w;
                } else {
                    pv[mi] += v * vw;
                }
            }
        }
#pragma unroll
    for (int mi = 0; mi < 4; ++mi) {
        int row_l = mi * 16 + m16;
        if (w < 4) {
#pragma unroll
            for (int a = 0; a < 4; ++a) {
                float x = pd[mi][a];
                x += __shfl_xor(x, 16); x += __shfl_xor(x, 32);
                if (quad == 0) redh[row_l][w][a] = x;
            }
        } else {
            float x = pv[mi];
            x += __shfl_xor(x, 16); x += __shfl_xor(x, 32);
            if (quad == 0) redh[row_l][w][0] = x;
        }
    }
    __syncthreads();
    if (tid < 64) {
        size_t o = (size_t)(m0 + tid) * 9;
#pragma unroll
        for (int a = 0; a < 4; ++a)
            out[o + a] = redh[tid][0][a] + redh[tid][1][a] + redh[tid][2][a] + redh[tid][3][a] + adb[a];
#pragma unroll
        for (int a = 0; a < 4; ++a) out[o + 4 + a] = expf(lstd[a]);
        out[o + 8] = redh[tid][4][0] + redh[tid][5][0] + redh[tid][6][0] + redh[tid][7][0] + vdb[0];
    }
}

// ======= enc0: A f32 (obs), staged to bf16 LDS in VGPRs; tile 64x128 ========
__global__ __launch_bounds__(256) void mgemm_obs(
    const float* __restrict__ A, const unsigned short* __restrict__ BT,
    unsigned short* __restrict__ U, const float* __restrict__ bias)
{
    const int K = 512, NJ = 2, N = 128;
    __shared__ unsigned short smA[64 * 32];
    __shared__ unsigned short smB[NJ * 64 * 32];
    int tid = threadIdx.x;
    int lane = tid & 63, w = tid >> 6;
    int m16 = lane & 15, quad = lane >> 4;
    int m0 = blockIdx.x * 64;

    f32x4 acc[4][NJ] = {};
    for (int k0 = 0; k0 < K; k0 += 32) {
#pragma unroll
        for (int p = 0; p < 2; ++p) {
            int idx = p * 256 + tid;
            int r = idx >> 3, kq = (idx & 7) * 4;
            float4 v = *(const float4*)(A + (size_t)(m0 + r) * K + k0 + kq);
            ushort4 o = { f2bf(v.x), f2bf(v.y), f2bf(v.z), f2bf(v.w) };
            *(ushort4*)(smA + r * 32 + kq) = o;
        }
#pragma unroll
        for (int p = 0; p < NJ; ++p) {
            const unsigned short* g = BT + (size_t)(p * 64 + (tid >> 2)) * K + k0 + (tid & 3) * 8;
            unsigned short* l = smB + p * 2048 + tid * 8;
            __builtin_amdgcn_global_load_lds(
                (const __attribute__((address_space(1))) void*)g,
                (__attribute__((address_space(3))) void*)l, 16, 0, 0);
        }
        __syncthreads();
        bf16x8 af[4], bfr[NJ];
#pragma unroll
        for (int mi = 0; mi < 4; ++mi)
            af[mi] = *(const bf16x8*)(smA + (mi * 16 + m16) * 32 + quad * 8);
#pragma unroll
        for (int nj = 0; nj < NJ; ++nj)
            bfr[nj] = *(const bf16x8*)(smB + (w * NJ * 16 + nj * 16 + m16) * 32 + quad * 8);
#pragma unroll
        for (int mi = 0; mi < 4; ++mi)
#pragma unroll
            for (int nj = 0; nj < NJ; ++nj)
                acc[mi][nj] = __builtin_amdgcn_mfma_f32_16x16x32_bf16(
                    bfr[nj], af[mi], acc[mi][nj], 0, 0, 0);
        __syncthreads();
    }
    int colb = w * NJ * 16 + quad * 4;
#pragma unroll
    for (int mi = 0; mi < 4; ++mi) {
        size_t rowb = (size_t)(m0 + mi * 16 + m16) * N;
#pragma unroll
        for (int nj = 0; nj < NJ; ++nj) {
            float4 bv = *(const float4*)(bias + colb + nj * 16);
            float v0 = acc[mi][nj][0] + bv.x; v0 = v0 > 0.f ? v0 : 0.01f * v0;
            float v1 = acc[mi][nj][1] + bv.y; v1 = v1 > 0.f ? v1 : 0.01f * v1;
            float v2 = acc[mi][nj][2] + bv.z; v2 = v2 > 0.f ? v2 : 0.01f * v2;
            float v3 = acc[mi][nj][3] + bv.w; v3 = v3 > 0.f ? v3 : 0.01f * v3;
            ushort4 o = { f2bf(v0), f2bf(v1), f2bf(v2), f2bf(v3) };
            *(ushort4*)(U + rowb + colb + nj * 16) = o;
        }
    }
}

// ------------- Chunk-parallel scan: 512 blocks (B x 4 p-phases) -------------
__global__ __launch_bounds__(512) void scan2_k(
    const unsigned short* __restrict__ bu, unsigned short* __restrict__ xs,
    const float* __restrict__ dones,
    const float* __restrict__ h0re, const float* __restrict__ h0im,
    const float* __restrict__ lamre, const float* __restrict__ lamim,
    const float* __restrict__ lstep,
    float* __restrict__ outre, float* __restrict__ outim)
{
    __shared__ float sdone[TT];
    __shared__ float4 ssum[16][32];
    __shared__ float2 shin[16][32];
    int tid = threadIdx.x;
    int b  = blockIdx.x >> 2;
    int ph = blockIdx.x & 3;
    int chunk = tid >> 5, pl = tid & 31;
    int p = ph * 32 + pl;
    sdone[tid] = dones[tid * BB + b];
    float lr = lamre[p], li = lamim[p];
    float st = expf(lstep[p]);
    float er = expf(lr * st);
    float ar = er * cosf(li * st);
    float ai = er * sinf(li * st);
    __syncthreads();

    int t0 = chunk * 32;
    unsigned buf[32];
    float Ar = 1.f, Ai = 0.f, br = 0.f, bi = 0.f;
#pragma unroll
    for (int j = 0; j < 32; ++j) {
        size_t off = ((size_t)(t0 + j) * BB + b) * 256 + 2 * p;
        unsigned v = *(const unsigned*)(bu + off);
        buf[j] = v;
        float bur = bf2f((unsigned short)(v & 0xFFFFu));
        float bui = bf2f((unsigned short)(v >> 16));
        if (sdone[t0 + j] != 0.f) {
            Ar = 0.f; Ai = 0.f; br = bur; bi = bui;
        } else {
            float nAr = ar * Ar - ai * Ai;
            float nAi = ar * Ai + ai * Ar;
            float nbr = fmaf(ar, br, fmaf(-ai, bi, bur));
            float nbi = fmaf(ar, bi, fmaf(ai, br, bui));
            Ar = nAr; Ai = nAi; br = nbr; bi = nbi;
        }
    }
    ssum[chunk][pl] = float4{Ar, Ai, br, bi};
    __syncthreads();
    if (tid < 32) {
        int gid = b * 128 + ph * 32 + tid;
        float hr = h0re[gid], hi = h0im[gid];
#pragma unroll
        for (int c = 0; c < 16; ++c) {
            shin[c][tid] = float2{hr, hi};
            float4 s = ssum[c][tid];
            float nhr = fmaf(s.x, hr, fmaf(-s.y, hi, s.z));
            float nhi = fmaf(s.x, hi, fmaf(s.y, hr, s.w));
            hr = nhr; hi = nhi;
        }
        outre[gid] = hr; outim[gid] = hi;
    }
    __syncthreads();
    float hr = shin[chunk][pl].x, hi = shin[chunk][pl].y;
#pragma unroll
    for (int j = 0; j < 32; ++j) {
        unsigned v = buf[j];
        float bur = bf2f((unsigned short)(v & 0xFFFFu));
        float bui = bf2f((unsigned short)(v >> 16));
        float nr, ni;
        if (sdone[t0 + j] != 0.f) { nr = bur; ni = bui; }
        else {
            nr = fmaf(ar, hr, fmaf(-ai, hi, bur));
            ni = fmaf(ar, hi, fmaf(ai, hr, bui));
        }
        hr = nr; hi = ni;
        size_t off = ((size_t)(t0 + j) * BB + b) * 256 + 2 * p;
        *(unsigned*)(xs + off) = ((unsigned)f2bf(ni) << 16) | f2bf(nr);
    }
}

// -- Precompute B_barT (interleaved n: 2p/2p+1) and CcatT (interleaved k) ----
__global__ __launch_bounds__(256) void prep_k(
    const float* __restrict__ Br, const float* __restrict__ Bi,
    const float* __restrict__ Cr, const float* __restrict__ Ci,
    const float* __restrict__ Lr, const float* __restrict__ Li,
    const float* __restrict__ ls, unsigned short* bbarT, unsigned short* ccatT)
{
    int gid = blockIdx.x * 256 + threadIdx.x;   // L*P*H = 131072
    int l = gid >> 15;
    int rem = gid & 32767;
    int p = rem >> 8;
    int h = rem & 255;
    float lr = Lr[l * PD + p], li = Li[l * PD + p];
    float st = expf(ls[l * PD + p]);
    float er = expf(lr * st);
    float lbr = er * cosf(li * st);
    float lbi = er * sinf(li * st);
    float nr = lbr - 1.f, ni = lbi;
    float den = lr * lr + li * li;
    float fr = (nr * lr + ni * li) / den;
    float fi = (ni * lr - nr * li) / den;
    float bre = Br[(size_t)(l * PD + p) * HD + h];
    float bim = Bi[(size_t)(l * PD + p) * HD + h];
    size_t lb = (size_t)l * 65536;
    bbarT[lb + (size_t)(2 * p) * 256 + h]     = f2bf(fr * bre - fi * bim);
    bbarT[lb + (size_t)(2 * p + 1) * 256 + h] = f2bf(fr * bim + fi * bre);
    float cre = Cr[(size_t)(l * HD + h) * PD + p];
    float cim = Ci[(size_t)(l * HD + h) * PD + p];
    ccatT[lb + (size_t)h * 256 + 2 * p]     = f2bf(2.f * cre);
    ccatT[lb + (size_t)h * 256 + 2 * p + 1] = f2bf(-2.f * cim);
}

// -------- transpose+convert: in f32 [K][N] -> out bf16 [N][K] ---------------
__global__ __launch_bounds__(256) void tcvt_k(const float* __restrict__ in,
    unsigned short* __restrict__ out, int K, int N)
{
    int gid = blockIdx.x * 256 + threadIdx.x;
    if (gid >= K * N) return;
    int k = gid / N, n = gid - k * N;
    out[(size_t)n * K + k] = f2bf(in[gid]);
}

// -------- 4x fused GLU transpose: in f32 [4][256][256] -> bf16 [4][256][256]^T
__global__ __launch_bounds__(256) void tcvt4_k(const float* __restrict__ in,
    unsigned short* __restrict__ out)
{
    int gid = blockIdx.x * 256 + threadIdx.x;   // 4*65536
    int l = gid >> 16;
    int rem = gid & 65535;
    int k = rem >> 8, n = rem & 255;
    out[(size_t)l * 65536 + (size_t)n * 256 + k] = f2bf(in[gid]);
}

// -------- concat two 128-f32 bias vectors into one 256-f32 ------------------
__global__ __launch_bounds__(256) void catb_k(const float* __restrict__ a,
    const float* __restrict__ b, float* __restrict__ out)
{
    int i = threadIdx.x;
    out[i] = (i < 128) ? a[i] : b[i - 128];
}

extern "C" void kernel_launch(void* const* d_in, const int* in_sizes, int n_in,
                              void* d_out, int out_size, void* d_ws, size_t ws_size,
                              hipStream_t stream) {
    (void)in_sizes; (void)n_in; (void)out_size; (void)ws_size;
    const float* obs     = (const float*)d_in[0];
    const float* dones   = (const float*)d_in[1];
    const float* hre     = (const float*)d_in[2];
    const float* him     = (const float*)d_in[3];
    const float* enc0_W  = (const float*)d_in[4];
    const float* enc0_b  = (const float*)d_in[5];
    const float* enc1_W  = (const float*)d_in[6];
    const float* enc1_b  = (const float*)d_in[7];
    const float* nsc     = (const float*)d_in[8];
    const float* nbi     = (const float*)d_in[9];
    const float* Lre     = (const float*)d_in[10];
    const float* Lim     = (const float*)d_in[11];
    const float* B_re    = (const float*)d_in[12];
    const float* B_im    = (const float*)d_in[13];
    const float* C_re    = (const float*)d_in[14];
    const float* C_im    = (const float*)d_in[15];
    const float* Dv      = (const float*)d_in[16];
    const float* lstep   = (const float*)d_in[17];
    const float* glu_W   = (const float*)d_in[18];
    const float* glu_b   = (const float*)d_in[19];
    const float* ab0_W   = (const float*)d_in[20];
    const float* ab0_b   = (const float*)d_in[21];
    const float* ab1_W   = (const float*)d_in[22];
    const float* ab1_b   = (const float*)d_in[23];
    const float* adec_W  = (const float*)d_in[24];
    const float* adec_b  = (const float*)d_in[25];
    const float* log_std = (const float*)d_in[26];
    const float* vb0_W   = (const float*)d_in[27];
    const float* vb0_b   = (const float*)d_in[28];
    const float* vb1_W   = (const float*)d_in[29];
    const float* vb1_b   = (const float*)d_in[30];
    const float* vdec_W  = (const float*)d_in[31];
    const float* vdec_b  = (const float*)d_in[32];

    const size_t MB = (size_t)1 << 20;
    char* wsb = (char*)d_ws;
    unsigned short* XS    = (unsigned short*)(wsb);              // 32MB (per-layer xs)
    unsigned short* U1    = (unsigned short*)(wsb + 64 * MB);    // 16MB (enc0 out)
    unsigned short* X     = (unsigned short*)(wsb + 96 * MB);    // 32MB residual bf16
    unsigned short* U     = (unsigned short*)(wsb + 128 * MB);   // 32MB (u / z)
    unsigned short* BU    = (unsigned short*)(wsb + 160 * MB);   // 32MB (Bu)
    char* wgt = wsb + 192 * MB;
    unsigned short* BBART = (unsigned short*)(wgt);                  // 512KB
    unsigned short* CCATT = (unsigned short*)(wgt + 512 * 1024);     // 512KB
    unsigned short* GLUT  = (unsigned short*)(wgt + 1024 * 1024);    // 512KB
    unsigned short* E0T   = (unsigned short*)(wgt + 1536 * 1024);    // 128KB
    unsigned short* E1T   = (unsigned short*)(wgt + 1664 * 1024);    // 64KB
    unsigned short* AB0VT = (unsigned short*)(wgt + 1728 * 1024);    // 128KB [AB0T;VB0T]
    unsigned short* AB1T  = (unsigned short*)(wgt + 1856 * 1024);    // 32KB
    unsigned short* VB1T  = (unsigned short*)(wgt + 1888 * 1024);    // 32KB
    float*          CB0   = (float*)(wgt + 1920 * 1024);             // 1KB [ab0_b|vb0_b]

    float* out   = (float*)d_out;
    float* outre = out + (size_t)NTB * 9;
    float* outim = outre + LD * BB * PD;

    // ---- weight prep ----
    prep_k<<<512, 256, 0, stream>>>(B_re, B_im, C_re, C_im, Lre, Lim, lstep, BBART, CCATT);
    tcvt_k<<<256, 256, 0, stream>>>(enc0_W, E0T, 512, 128);
    tcvt_k<<<128, 256, 0, stream>>>(enc1_W, E1T, 128, 256);
    tcvt4_k<<<1024, 256, 0, stream>>>(glu_W, GLUT);
    tcvt_k<<<128, 256, 0, stream>>>(ab0_W, AB0VT, 256, 128);                 // rows 0..127
    tcvt_k<<<128, 256, 0, stream>>>(vb0_W, AB0VT + 128 * 256, 256, 128);     // rows 128..255
    tcvt_k<<<64, 256, 0, stream>>>(ab1_W, AB1T, 128, 128);
    tcvt_k<<<64, 256, 0, stream>>>(vb1_W, VB1T, 128, 128);
    catb_k<<<1, 256, 0, stream>>>(ab0_b, vb0_b, CB0);

    // ---- encoder ----
    mgemm_obs<<<1024, 256, 0, stream>>>(obs, E0T, U1, enc0_b);
    // enc1 fused: X = leaky(U1@E1+b), U = LN_0(X)
    mgemm2<0, 4, 4><<<1024, 512, 0, stream>>>(U1, E1T, 128, enc1_b, nsc, nbi, nullptr, X, U, 1);

    // ---- S5 layers ----
    // Bu for layer 0 (layers 1..3 get BU from glu_bu_k)
    mgemm2<1, 4, 8><<<1024, 512, 0, stream>>>(U, BBART, 256,
                                           nullptr, nullptr, nullptr, nullptr, nullptr, BU, 0);
    for (int l = 0; l < LD; ++l) {
        scan2_k<<<512, 512, 0, stream>>>(BU, XS, dones, hre + l * BB * PD, him + l * BB * PD,
                                         Lre + l * PD, Lim + l * PD, lstep + l * PD,
                                         outre + l * BB * PD, outim + l * BB * PD);
        // z = gelu(LN_l(xs@C + D*u))   (in-place U: aux1=U read, U written)
        mgemm2<2, 4, 8><<<1024, 512, 0, stream>>>(XS, CCATT + (size_t)l * 65536, 256,
                                               Dv + l * HD, nsc + l * HD, nbi + l * HD, U, nullptr, U, 1);
        if (l + 1 < LD) {
            // fused: x += z*sig(z@W+b); u' = LN_{l+1}(x) -> U & LDS; BU = u'@Bbar_{l+1}
            glu_bu_k<<<1024, 512, 0, stream>>>(U, GLUT + (size_t)l * 65536,
                                               BBART + (size_t)(l + 1) * 65536,
                                               glu_b + l * HD,
                                               nsc + (l + 1) * HD, nbi + (l + 1) * HD,
                                               X, U, BU);
        } else {
            // last layer: plain GLU, no LN2/Bu
            mgemm2<3, 4, 8><<<1024, 512, 0, stream>>>(U, GLUT + (size_t)l * 65536, 256,
                                               glu_b + l * HD, nsc, nbi, U, X, U, 0);
        }
    }

    // ---- heads: fully fused X -> out ----
    head_fused_k<<<1024, 512, 0, stream>>>(X, AB0VT, CB0, AB1T, VB1T, ab1_b, vb1_b,
                                           adec_W, adec_b, log_std, vdec_W, vdec_b, out);
}